// Round 9
// baseline (286.291 us; speedup 1.0000x reference)
//
#include <hip/hip_runtime.h>

#define IN_DIM 256
#define HID 64
#define HEADS 4
#define C1 256   // HID*HEADS

typedef __attribute__((ext_vector_type(4))) float  f32x4;
typedef __attribute__((ext_vector_type(8))) short  short8;
typedef __attribute__((ext_vector_type(8))) unsigned short ushort8;
typedef __attribute__((ext_vector_type(4))) unsigned short ushort4v;

static __device__ __forceinline__ unsigned short f2bf(float f) {
  union { float f; unsigned int u; } v; v.f = f;
  unsigned int r = v.u + 0x7fffu + ((v.u >> 16) & 1u);   // RNE
  return (unsigned short)(r >> 16);
}
static __device__ __forceinline__ float bf2f(unsigned short u) {
  union { unsigned int u; float f; } v; v.u = ((unsigned int)u) << 16;
  return v.f;
}

// ---------------------------------------------------------------------------
// CSR build
// ---------------------------------------------------------------------------

__global__ __launch_bounds__(256) void zero_int_kernel(int* __restrict__ p, int n) {
  int i = blockIdx.x * 256 + threadIdx.x;
  if (i < n) p[i] = 0;
}

__global__ __launch_bounds__(256) void hist_kernel(const int* __restrict__ ei,
                                                   int E, int N, int* __restrict__ counts) {
  int e = blockIdx.x * 256 + threadIdx.x;
  if (e >= E + N) return;
  int dst = (e < E) ? ei[(size_t)E + e] : (e - E);
  atomicAdd(&counts[dst], 1);
}

__global__ __launch_bounds__(256) void scan1_kernel(const int* __restrict__ counts,
                                                    int* __restrict__ blocksums, int N) {
  int tid = threadIdx.x;
  int base = blockIdx.x * 1024 + tid * 4;
  int s = 0;
  if (base + 3 < N) {
    int4 v = *(const int4*)&counts[base];
    s = v.x + v.y + v.z + v.w;
  } else {
    for (int i = 0; i < 4; ++i) if (base + i < N) s += counts[base + i];
  }
  __shared__ int red[256];
  red[tid] = s;
  __syncthreads();
  for (int off = 128; off; off >>= 1) {
    if (tid < off) red[tid] += red[tid + off];
    __syncthreads();
  }
  if (tid == 0) blocksums[blockIdx.x] = red[0];
}

__global__ __launch_bounds__(64) void scan2_kernel(const int* __restrict__ blocksums,
                                                   int* __restrict__ blockoff, int B) {
  int lane = threadIdx.x;
  int carry = 0;
  for (int base = 0; base < B; base += 64) {
    int v = (base + lane < B) ? blocksums[base + lane] : 0;
    int incl = v;
    #pragma unroll
    for (int off = 1; off < 64; off <<= 1) {
      int t = __shfl_up(incl, off);
      if (lane >= off) incl += t;
    }
    if (base + lane < B) blockoff[base + lane] = carry + incl - v;
    carry += __shfl(incl, 63);
  }
  if (lane == 0) blockoff[B] = carry;
}

__global__ __launch_bounds__(256) void scan3_kernel(const int* __restrict__ counts,
                                                    const int* __restrict__ blockoff,
                                                    int* __restrict__ indptr,
                                                    int* __restrict__ fillpos, int N) {
  int tid = threadIdx.x;
  int base = blockIdx.x * 1024 + tid * 4;
  int c0 = 0, c1 = 0, c2 = 0, c3 = 0;
  if (base + 3 < N) {
    int4 v = *(const int4*)&counts[base];
    c0 = v.x; c1 = v.y; c2 = v.z; c3 = v.w;
  } else {
    if (base + 0 < N) c0 = counts[base + 0];
    if (base + 1 < N) c1 = counts[base + 1];
    if (base + 2 < N) c2 = counts[base + 2];
    if (base + 3 < N) c3 = counts[base + 3];
  }
  int s = c0 + c1 + c2 + c3;
  __shared__ int sc[256];
  sc[tid] = s;
  __syncthreads();
  for (int off = 1; off < 256; off <<= 1) {
    int t = (tid >= off) ? sc[tid - off] : 0;
    __syncthreads();
    sc[tid] += t;
    __syncthreads();
  }
  int p = sc[tid] - s + blockoff[blockIdx.x];
  if (base + 0 < N) { indptr[base + 0] = p; fillpos[base + 0] = p; p += c0; }
  if (base + 1 < N) { indptr[base + 1] = p; fillpos[base + 1] = p; p += c1; }
  if (base + 2 < N) { indptr[base + 2] = p; fillpos[base + 2] = p; p += c2; }
  if (base + 3 < N) { indptr[base + 3] = p; fillpos[base + 3] = p; p += c3; }
  if (blockIdx.x == 0 && tid == 0) indptr[N] = blockoff[gridDim.x];
}

__global__ __launch_bounds__(256) void fill_kernel(const int* __restrict__ ei, int E, int N,
                                                   int* __restrict__ fillpos,
                                                   int* __restrict__ srcs) {
  int e = blockIdx.x * 256 + threadIdx.x;
  if (e >= E + N) return;
  int src, dst;
  if (e < E) { src = ei[e]; dst = ei[(size_t)E + e]; }
  else       { src = e - E; dst = e - E; }
  int pos = atomicAdd(&fillpos[dst], 1);
  srcs[pos] = src;
}

// ---------------------------------------------------------------------------
// W[k][n] (f32, KxNC) -> Wt[n][k] (bf16, NCxK)
// ---------------------------------------------------------------------------

__global__ __launch_bounds__(256) void convwt_kernel(const float* __restrict__ W,
                                                     unsigned short* __restrict__ Wt,
                                                     int K, int NC) {
  int t = blockIdx.x * 256 + threadIdx.x;
  if (t >= K * NC) return;
  int k = t & (K - 1);
  int n = t >> 8;
  Wt[(size_t)n * K + k] = f2bf(W[(size_t)k * NC + n]);
}

// ---------------------------------------------------------------------------
// bf16 MFMA GEMM, BM=64, BK=64, BN template (64 or 128).
// AF32: A is f32, converted during LDS staging (coalesced 64B/lane reads).
// 4 waves in 2x2; each wave 32 x (BN/2); acc[2][BN/32] frags of 16x16x32.
// ---------------------------------------------------------------------------

#define LDT2 72   // padded LDS row stride (elements)

template<bool AF32, int BN>
__global__ __launch_bounds__(256) void gemm64_kernel(const void* __restrict__ Av,
                                                     const unsigned short* __restrict__ Bt,
                                                     unsigned short* __restrict__ C,
                                                     int M, int NC, int K) {
  const int NF = BN / 32;                 // col frags per wave
  __shared__ unsigned short As[64 * LDT2];
  __shared__ unsigned short Bs[BN * LDT2];
  int bm = blockIdx.x * 64, bn = blockIdx.y * BN;
  int tid = threadIdx.x;
  int wid = tid >> 6, lane = tid & 63;
  int wr = (wid >> 1) * 32, wc = (wid & 1) * (BN / 2);
  int l15 = lane & 15, lq = lane >> 4;

  f32x4 acc[2][NF];
  #pragma unroll
  for (int i = 0; i < 2; ++i)
    #pragma unroll
    for (int f = 0; f < NF; ++f) acc[i][f] = (f32x4){0,0,0,0};

  for (int k0 = 0; k0 < K; k0 += 64) {
    // ---- stage A (64 rows x 64 k): row = tid>>2, cols (tid&3)*16..+15 ----
    {
      int r = tid >> 2, c = (tid & 3) * 16;
      int row = bm + r;
      if (AF32) {
        const float* A = (const float*)Av;
        ushort4v o[4];
        #pragma unroll
        for (int p = 0; p < 4; ++p) {
          float4 v = make_float4(0.f, 0.f, 0.f, 0.f);
          if (row < M) v = *(const float4*)&A[(size_t)row * K + k0 + c + p * 4];
          o[p][0]=f2bf(v.x); o[p][1]=f2bf(v.y); o[p][2]=f2bf(v.z); o[p][3]=f2bf(v.w);
        }
        #pragma unroll
        for (int p = 0; p < 4; ++p)
          *(ushort4v*)&As[r * LDT2 + c + p * 4] = o[p];
      } else {
        const unsigned short* A = (const unsigned short*)Av;
        ushort8 v0 = {0,0,0,0,0,0,0,0}, v1 = {0,0,0,0,0,0,0,0};
        if (row < M) {
          v0 = *(const ushort8*)&A[(size_t)row * K + k0 + c];
          v1 = *(const ushort8*)&A[(size_t)row * K + k0 + c + 8];
        }
        *(ushort8*)&As[r * LDT2 + c]     = v0;
        *(ushort8*)&As[r * LDT2 + c + 8] = v1;
      }
    }
    // ---- stage B (BN rows x 64 k) ----
    #pragma unroll
    for (int p = 0; p < BN / 64; ++p) {
      int r = p * 64 + (tid >> 2), seg = (tid & 3) * 16;
      ushort8 v0 = *(const ushort8*)&Bt[(size_t)(bn + r) * K + k0 + seg];
      ushort8 v1 = *(const ushort8*)&Bt[(size_t)(bn + r) * K + k0 + seg + 8];
      *(ushort8*)&Bs[r * LDT2 + seg]     = v0;
      *(ushort8*)&Bs[r * LDT2 + seg + 8] = v1;
    }
    __syncthreads();

    #pragma unroll
    for (int ks = 0; ks < 2; ++ks) {
      short8 a0 = *(const short8*)&As[(wr + l15) * LDT2 + ks * 32 + lq * 8];
      short8 a1 = *(const short8*)&As[(wr + 16 + l15) * LDT2 + ks * 32 + lq * 8];
      #pragma unroll
      for (int f = 0; f < NF; ++f) {
        short8 b = *(const short8*)&Bs[(wc + f * 16 + l15) * LDT2 + ks * 32 + lq * 8];
        acc[0][f] = __builtin_amdgcn_mfma_f32_16x16x32_bf16(a0, b, acc[0][f], 0, 0, 0);
        acc[1][f] = __builtin_amdgcn_mfma_f32_16x16x32_bf16(a1, b, acc[1][f], 0, 0, 0);
      }
    }
    __syncthreads();
  }

  // C/D layout: col = lane&15, row = (lane>>4)*4 + reg
  #pragma unroll
  for (int r = 0; r < 4; ++r) {
    int row0 = bm + wr + lq * 4 + r;
    int row1 = row0 + 16;
    #pragma unroll
    for (int f = 0; f < NF; ++f) {
      int col = bn + wc + f * 16 + l15;
      if (row0 < M) C[(size_t)row0 * NC + col] = f2bf(acc[0][f][r]);
      if (row1 < M) C[(size_t)row1 * NC + col] = f2bf(acc[1][f][r]);
    }
  }
}

// ---------------------------------------------------------------------------
// Attention logit projections (bf16 H)
// ---------------------------------------------------------------------------

__global__ __launch_bounds__(256) void alpha1_kernel(const unsigned short* __restrict__ H1b,
                                                     const float* __restrict__ a_src,
                                                     const float* __restrict__ a_dst,
                                                     float* __restrict__ asrc,
                                                     float* __restrict__ adst, int N) {
  int n = blockIdx.x * 4 + (threadIdx.x >> 6);
  if (n >= N) return;
  int lane = threadIdx.x & 63;
  int h = lane >> 4;
  ushort4v raw = *(const ushort4v*)&H1b[(size_t)n * C1 + lane * 4];
  float4 as = *(const float4*)&a_src[h * HID + (lane & 15) * 4];
  float4 ad = *(const float4*)&a_dst[h * HID + (lane & 15) * 4];
  float h0 = bf2f(raw[0]), h1 = bf2f(raw[1]), h2 = bf2f(raw[2]), h3 = bf2f(raw[3]);
  float vs = h0 * as.x + h1 * as.y + h2 * as.z + h3 * as.w;
  float vd = h0 * ad.x + h1 * ad.y + h2 * ad.z + h3 * ad.w;
  #pragma unroll
  for (int off = 1; off < 16; off <<= 1) {
    vs += __shfl_xor(vs, off);
    vd += __shfl_xor(vd, off);
  }
  if ((lane & 15) == 0) {
    asrc[n * HEADS + h] = vs;
    adst[n * HEADS + h] = vd;
  }
}

__global__ __launch_bounds__(256) void alpha2_kernel(const unsigned short* __restrict__ H2b,
                                                     const float* __restrict__ a_src,
                                                     const float* __restrict__ a_dst,
                                                     float* __restrict__ asrc,
                                                     float* __restrict__ adst, int N) {
  int n = blockIdx.x * 4 + (threadIdx.x >> 6);
  if (n >= N) return;
  int lane = threadIdx.x & 63;
  int j = lane & 31;
  unsigned int raw = *(const unsigned int*)&H2b[(size_t)n * HID + j * 2];
  float h0 = bf2f((unsigned short)(raw & 0xffff));
  float h1 = bf2f((unsigned short)(raw >> 16));
  float vs = h0 * a_src[j * 2] + h1 * a_src[j * 2 + 1];
  float vd = h0 * a_dst[j * 2] + h1 * a_dst[j * 2 + 1];
  #pragma unroll
  for (int off = 1; off < 32; off <<= 1) {
    vs += __shfl_xor(vs, off);
    vd += __shfl_xor(vd, off);
  }
  if (lane == 0) { asrc[n] = vs; adst[n] = vd; }
}

// ---------------------------------------------------------------------------
// Edge softmax weights, dst-major (wave per node): adst wave-uniform,
// w writes coalesced, no edst array needed.
// ---------------------------------------------------------------------------

// 16 edges x 4 heads per iter; lane = (slot = l>>2, h = l&3)
__global__ __launch_bounds__(256) void edgew1_kernel(const int* __restrict__ indptr,
                                                     const int* __restrict__ srcs,
                                                     const float* __restrict__ asrc,
                                                     const float* __restrict__ adst,
                                                     float* __restrict__ w, int N) {
  int n = blockIdx.x * 4 + (threadIdx.x >> 6);
  if (n >= N) return;
  int lane = threadIdx.x & 63;
  int slot = lane >> 2, h = lane & 3;
  int start = indptr[n], end = indptr[n + 1];
  float ad = adst[n * HEADS + h];
  for (int base = start; base < end; base += 16) {
    int k = base + slot;
    if (k < end) {
      float e = asrc[srcs[k] * HEADS + h] + ad;
      e = (e > 0.f) ? e : 0.2f * e;
      w[k * 4 + h] = __expf(e);
    }
  }
}

// 64 edges per iter
__global__ __launch_bounds__(256) void edgew2_kernel(const int* __restrict__ indptr,
                                                     const int* __restrict__ srcs,
                                                     const float* __restrict__ asrc,
                                                     const float* __restrict__ adst,
                                                     float* __restrict__ w, int N) {
  int n = blockIdx.x * 4 + (threadIdx.x >> 6);
  if (n >= N) return;
  int lane = threadIdx.x & 63;
  int start = indptr[n], end = indptr[n + 1];
  float ad = adst[n];
  for (int k = start + lane; k < end; k += 64) {
    float e = asrc[srcs[k]] + ad;
    e = (e > 0.f) ? e : 0.2f * e;
    w[k] = __expf(e);
  }
}

// ---------------------------------------------------------------------------
// GAT agg layer 1: wave per node, split-wave (2 edges), 16B/lane, 2x unroll.
// lane = (half = l>>5, j = l&31); feats 8j..8j+7; head h = j>>3.
// ---------------------------------------------------------------------------

__global__ __launch_bounds__(256) void gat1_agg(const unsigned short* __restrict__ H1b,
                                                const float* __restrict__ w,
                                                const int* __restrict__ indptr,
                                                const int* __restrict__ srcs,
                                                const float* __restrict__ b1,
                                                const float* __restrict__ g1,
                                                const float* __restrict__ be1,
                                                const float* __restrict__ mu1,
                                                const float* __restrict__ var1,
                                                unsigned short* __restrict__ X2b, int N) {
  int n = blockIdx.x * 4 + (threadIdx.x >> 6);
  if (n >= N) return;
  int lane = threadIdx.x & 63;
  int half = lane >> 5;
  int j = lane & 31;
  int h = j >> 3;
  int start = indptr[n], end = indptr[n + 1];

  float acc[8] = {0.f,0.f,0.f,0.f,0.f,0.f,0.f,0.f};
  float wsum = 0.f;
  int k = start + half;
  // unrolled: 2 edges per half-wave in flight
  for (; k + 2 < end; k += 4) {
    int s0 = srcs[k], s1 = srcs[k + 2];
    float w0 = w[k * 4 + h], w1v = w[(k + 2) * 4 + h];
    ushort8 r0 = *(const ushort8*)&H1b[(size_t)s0 * C1 + j * 8];
    ushort8 r1 = *(const ushort8*)&H1b[(size_t)s1 * C1 + j * 8];
    wsum += w0 + w1v;
    #pragma unroll
    for (int i = 0; i < 8; ++i)
      acc[i] += w0 * bf2f(r0[i]) + w1v * bf2f(r1[i]);
  }
  for (; k < end; k += 2) {
    int s0 = srcs[k];
    float w0 = w[k * 4 + h];
    ushort8 r0 = *(const ushort8*)&H1b[(size_t)s0 * C1 + j * 8];
    wsum += w0;
    #pragma unroll
    for (int i = 0; i < 8; ++i) acc[i] += w0 * bf2f(r0[i]);
  }
  #pragma unroll
  for (int i = 0; i < 8; ++i) acc[i] += __shfl_xor(acc[i], 32);
  wsum += __shfl_xor(wsum, 32);

  if (half == 0) {
    float inv = 1.f / (wsum + 1e-16f);
    int f = j * 8;
    ushort8 o;
    #pragma unroll
    for (int i = 0; i < 8; ++i) {
      float val = (acc[i] * inv + b1[f + i] - mu1[f + i]) *
                  (g1[f + i] * rsqrtf(var1[f + i] + 1e-5f)) + be1[f + i];
      val = (val > 0.f) ? val : (__expf(val) - 1.f);
      o[i] = f2bf(val);
    }
    *(ushort8*)&X2b[(size_t)n * C1 + f] = o;
  }
}

// ---------------------------------------------------------------------------
// GAT agg layer 2: wave per node, 8 edge slots, 16B/lane features.
// ---------------------------------------------------------------------------

__global__ __launch_bounds__(256) void gat2_agg(const unsigned short* __restrict__ H2b,
                                                const float* __restrict__ w,
                                                const int* __restrict__ indptr,
                                                const int* __restrict__ srcs,
                                                const float* __restrict__ b2,
                                                const float* __restrict__ g2,
                                                const float* __restrict__ be2,
                                                const float* __restrict__ mu2,
                                                const float* __restrict__ var2,
                                                float* __restrict__ out, int N) {
  int n = blockIdx.x * 4 + (threadIdx.x >> 6);
  if (n >= N) return;
  int lane = threadIdx.x & 63;
  int q = lane >> 3;
  int j = lane & 7;
  int start = indptr[n], end = indptr[n + 1];

  float acc[8];
  #pragma unroll
  for (int i = 0; i < 8; ++i) acc[i] = 0.f;
  float wsum = 0.f;

  for (int k = start + q; k < end; k += 8) {
    int s = srcs[k];
    float wt = w[k];
    ushort8 raw = *(const ushort8*)&H2b[(size_t)s * HID + j * 8];
    wsum += wt;
    #pragma unroll
    for (int i = 0; i < 8; ++i) acc[i] += wt * bf2f(raw[i]);
  }
  #pragma unroll
  for (int i = 0; i < 8; ++i) {
    acc[i] += __shfl_xor(acc[i], 8);
    acc[i] += __shfl_xor(acc[i], 16);
    acc[i] += __shfl_xor(acc[i], 32);
  }
  wsum += __shfl_xor(wsum, 8);
  wsum += __shfl_xor(wsum, 16);
  wsum += __shfl_xor(wsum, 32);

  if (q == 0) {
    float inv = 1.f / (wsum + 1e-16f);
    int f = j * 8;
    float o[8];
    #pragma unroll
    for (int i = 0; i < 8; ++i) {
      float val = (acc[i] * inv + b2[f + i] - mu2[f + i]) *
                  (g2[f + i] * rsqrtf(var2[f + i] + 1e-5f)) + be2[f + i];
      o[i] = (val > 0.f) ? val : (__expf(val) - 1.f);
    }
    *(float4*)&out[(size_t)n * HID + f]     = make_float4(o[0], o[1], o[2], o[3]);
    *(float4*)&out[(size_t)n * HID + f + 4] = make_float4(o[4], o[5], o[6], o[7]);
  }
}

// ---------------------------------------------------------------------------

extern "C" void kernel_launch(void* const* d_in, const int* in_sizes, int n_in,
                              void* d_out, int out_size, void* d_ws, size_t ws_size,
                              hipStream_t stream) {
  const float* x      = (const float*)d_in[0];
  const int*   ei     = (const int*)d_in[1];
  const float* W1     = (const float*)d_in[2];
  const float* a_src1 = (const float*)d_in[3];
  const float* a_dst1 = (const float*)d_in[4];
  const float* b1     = (const float*)d_in[5];
  const float* g1     = (const float*)d_in[6];
  const float* be1    = (const float*)d_in[7];
  const float* mu1    = (const float*)d_in[8];
  const float* var1   = (const float*)d_in[9];
  const float* W2     = (const float*)d_in[10];
  const float* a_src2 = (const float*)d_in[11];
  const float* a_dst2 = (const float*)d_in[12];
  const float* b2     = (const float*)d_in[13];
  const float* g2     = (const float*)d_in[14];
  const float* be2    = (const float*)d_in[15];
  const float* mu2    = (const float*)d_in[16];
  const float* var2   = (const float*)d_in[17];
  float* out = (float*)d_out;

  int N = in_sizes[0] / IN_DIM;
  int E = in_sizes[1] / 2;
  int Etot = E + N;
  int NB = (N + 1023) / 1024;

  // Workspace (~72 MB):
  //   H1b[N*256]b (reused H2b) | X2b[N*256]b | W1t[256*256]b | W2t[64*256]b |
  //   w1[4*Etot]f (reused w2) | asrc1[4N]f | adst1[4N]f | asrc2[N]f |
  //   adst2[N]f | counts[N] | indptr[N+1] | fillpos[N] | blocksums[NB] |
  //   blockoff[NB+1] | srcs[Etot]
  unsigned short* H1b = (unsigned short*)d_ws;
  unsigned short* X2b = H1b + (size_t)N * C1;
  unsigned short* W1t = X2b + (size_t)N * C1;
  unsigned short* W2t = W1t + 256 * 256;
  float* w1    = (float*)(W2t + 64 * 256);
  float* asrc1 = w1 + (size_t)4 * Etot;
  float* adst1 = asrc1 + (size_t)N * HEADS;
  float* asrc2 = adst1 + (size_t)N * HEADS;
  float* adst2 = asrc2 + N;
  int* counts    = (int*)(adst2 + N);
  int* indptr    = counts + N;
  int* fillpos   = indptr + (N + 1);
  int* blocksums = fillpos + N;
  int* blockoff  = blocksums + NB;
  int* srcs      = blockoff + (NB + 1);
  unsigned short* H2b = H1b;   // H1b dead after gat1_agg
  float* w2 = w1;              // w1 dead before edgew2

  // --- CSR build ---
  zero_int_kernel<<<(N + 255) / 256, 256, 0, stream>>>(counts, N);
  hist_kernel<<<(Etot + 255) / 256, 256, 0, stream>>>(ei, E, N, counts);
  scan1_kernel<<<NB, 256, 0, stream>>>(counts, blocksums, N);
  scan2_kernel<<<1, 64, 0, stream>>>(blocksums, blockoff, NB);
  scan3_kernel<<<NB, 256, 0, stream>>>(counts, blockoff, indptr, fillpos, N);
  fill_kernel<<<(Etot + 255) / 256, 256, 0, stream>>>(ei, E, N, fillpos, srcs);

  // --- Weight transposes ---
  convwt_kernel<<<(256 * 256 + 255) / 256, 256, 0, stream>>>(W1, W1t, 256, C1);
  convwt_kernel<<<(256 * 64 + 255) / 256, 256, 0, stream>>>(W2, W2t, 256, HID);

  // --- Layer 1 (A = x f32 converted in staging; BN=128) ---
  gemm64_kernel<true, 128><<<dim3((N + 63) / 64, C1 / 128), 256, 0, stream>>>(x, W1t, H1b, N, C1, IN_DIM);
  alpha1_kernel<<<(N + 3) / 4, 256, 0, stream>>>(H1b, a_src1, a_dst1, asrc1, adst1, N);
  edgew1_kernel<<<(N + 3) / 4, 256, 0, stream>>>(indptr, srcs, asrc1, adst1, w1, N);
  gat1_agg<<<(N + 3) / 4, 256, 0, stream>>>(H1b, w1, indptr, srcs,
                                            b1, g1, be1, mu1, var1, X2b, N);

  // --- Layer 2 (A = X2b bf16; BN=64) ---
  gemm64_kernel<false, 64><<<dim3((N + 63) / 64, HID / 64), 256, 0, stream>>>(X2b, W2t, H2b, N, HID, C1);
  alpha2_kernel<<<(N + 3) / 4, 256, 0, stream>>>(H2b, a_src2, a_dst2, asrc2, adst2, N);
  edgew2_kernel<<<(N + 3) / 4, 256, 0, stream>>>(indptr, srcs, asrc2, adst2, w2, N);
  gat2_agg<<<(N + 3) / 4, 256, 0, stream>>>(H2b, w2, indptr, srcs,
                                            b2, g2, be2, mu2, var2, out, N);
}

// Round 10
// 246.348 us; speedup vs baseline: 1.1621x; 1.1621x over previous
//
#include <hip/hip_runtime.h>

#define IN_DIM 256
#define HID 64
#define HEADS 4
#define C1 256   // HID*HEADS

typedef __attribute__((ext_vector_type(4))) float  f32x4;
typedef __attribute__((ext_vector_type(8))) short  short8;
typedef __attribute__((ext_vector_type(8))) unsigned short ushort8;
typedef __attribute__((ext_vector_type(4))) unsigned short ushort4v;

static __device__ __forceinline__ unsigned short f2bf(float f) {
  union { float f; unsigned int u; } v; v.f = f;
  unsigned int r = v.u + 0x7fffu + ((v.u >> 16) & 1u);   // RNE
  return (unsigned short)(r >> 16);
}
static __device__ __forceinline__ float bf2f(unsigned short u) {
  union { unsigned int u; float f; } v; v.u = ((unsigned int)u) << 16;
  return v.f;
}

// ---------------------------------------------------------------------------
// CSR build
// ---------------------------------------------------------------------------

__global__ __launch_bounds__(256) void zero_int_kernel(int* __restrict__ p, int n) {
  int i = blockIdx.x * 256 + threadIdx.x;
  if (i < n) p[i] = 0;
}

__global__ __launch_bounds__(256) void hist_kernel(const int* __restrict__ ei,
                                                   int E, int N, int* __restrict__ counts) {
  int e = blockIdx.x * 256 + threadIdx.x;
  if (e >= E + N) return;
  int dst = (e < E) ? ei[(size_t)E + e] : (e - E);
  atomicAdd(&counts[dst], 1);
}

__global__ __launch_bounds__(256) void scan1_kernel(const int* __restrict__ counts,
                                                    int* __restrict__ blocksums, int N) {
  int tid = threadIdx.x;
  int base = blockIdx.x * 1024 + tid * 4;
  int s = 0;
  if (base + 3 < N) {
    int4 v = *(const int4*)&counts[base];
    s = v.x + v.y + v.z + v.w;
  } else {
    for (int i = 0; i < 4; ++i) if (base + i < N) s += counts[base + i];
  }
  __shared__ int red[256];
  red[tid] = s;
  __syncthreads();
  for (int off = 128; off; off >>= 1) {
    if (tid < off) red[tid] += red[tid + off];
    __syncthreads();
  }
  if (tid == 0) blocksums[blockIdx.x] = red[0];
}

__global__ __launch_bounds__(64) void scan2_kernel(const int* __restrict__ blocksums,
                                                   int* __restrict__ blockoff, int B) {
  int lane = threadIdx.x;
  int carry = 0;
  for (int base = 0; base < B; base += 64) {
    int v = (base + lane < B) ? blocksums[base + lane] : 0;
    int incl = v;
    #pragma unroll
    for (int off = 1; off < 64; off <<= 1) {
      int t = __shfl_up(incl, off);
      if (lane >= off) incl += t;
    }
    if (base + lane < B) blockoff[base + lane] = carry + incl - v;
    carry += __shfl(incl, 63);
  }
  if (lane == 0) blockoff[B] = carry;
}

__global__ __launch_bounds__(256) void scan3_kernel(const int* __restrict__ counts,
                                                    const int* __restrict__ blockoff,
                                                    int* __restrict__ indptr,
                                                    int* __restrict__ fillpos, int N) {
  int tid = threadIdx.x;
  int base = blockIdx.x * 1024 + tid * 4;
  int c0 = 0, c1 = 0, c2 = 0, c3 = 0;
  if (base + 3 < N) {
    int4 v = *(const int4*)&counts[base];
    c0 = v.x; c1 = v.y; c2 = v.z; c3 = v.w;
  } else {
    if (base + 0 < N) c0 = counts[base + 0];
    if (base + 1 < N) c1 = counts[base + 1];
    if (base + 2 < N) c2 = counts[base + 2];
    if (base + 3 < N) c3 = counts[base + 3];
  }
  int s = c0 + c1 + c2 + c3;
  __shared__ int sc[256];
  sc[tid] = s;
  __syncthreads();
  for (int off = 1; off < 256; off <<= 1) {
    int t = (tid >= off) ? sc[tid - off] : 0;
    __syncthreads();
    sc[tid] += t;
    __syncthreads();
  }
  int p = sc[tid] - s + blockoff[blockIdx.x];
  if (base + 0 < N) { indptr[base + 0] = p; fillpos[base + 0] = p; p += c0; }
  if (base + 1 < N) { indptr[base + 1] = p; fillpos[base + 1] = p; p += c1; }
  if (base + 2 < N) { indptr[base + 2] = p; fillpos[base + 2] = p; p += c2; }
  if (base + 3 < N) { indptr[base + 3] = p; fillpos[base + 3] = p; p += c3; }
  if (blockIdx.x == 0 && tid == 0) indptr[N] = blockoff[gridDim.x];
}

// fill fused with layer-1 edge weights: one pass over edges writes both
// the CSR src list and w1 = exp(leaky_relu(asrc[src]+adst[dst])) per head.
__global__ __launch_bounds__(256) void fillw_kernel(const int* __restrict__ ei, int E, int N,
                                                    int* __restrict__ fillpos,
                                                    int* __restrict__ srcs,
                                                    const float* __restrict__ asrc,
                                                    const float* __restrict__ adst,
                                                    float* __restrict__ w) {
  int e = blockIdx.x * 256 + threadIdx.x;
  if (e >= E + N) return;
  int src, dst;
  if (e < E) { src = ei[e]; dst = ei[(size_t)E + e]; }
  else       { src = e - E; dst = e - E; }
  int pos = atomicAdd(&fillpos[dst], 1);
  srcs[pos] = src;
  float4 as = *(const float4*)&asrc[src * 4];
  float4 ad = *(const float4*)&adst[dst * 4];
  float e0 = as.x + ad.x; e0 = (e0 > 0.f) ? e0 : 0.2f * e0;
  float e1 = as.y + ad.y; e1 = (e1 > 0.f) ? e1 : 0.2f * e1;
  float e2 = as.z + ad.z; e2 = (e2 > 0.f) ? e2 : 0.2f * e2;
  float e3 = as.w + ad.w; e3 = (e3 > 0.f) ? e3 : 0.2f * e3;
  *(float4*)&w[pos * 4] = make_float4(__expf(e0), __expf(e1), __expf(e2), __expf(e3));
}

// ---------------------------------------------------------------------------
// Both weight transposes in one kernel: W[k][n] f32 -> Wt[n][k] bf16
// ---------------------------------------------------------------------------

__global__ __launch_bounds__(256) void convw_kernel(const float* __restrict__ W1,
                                                    unsigned short* __restrict__ W1t,
                                                    const float* __restrict__ W2,
                                                    unsigned short* __restrict__ W2t) {
  int t = blockIdx.x * 256 + threadIdx.x;
  if (t < 256 * 256) {
    int k = t & 255, n = t >> 8;
    W1t[n * 256 + k] = f2bf(W1[k * 256 + n]);
  } else if (t < 256 * 256 + 64 * 256) {
    int u = t - 256 * 256;
    int k = u & 255, n = u >> 8;
    W2t[n * 256 + k] = f2bf(W2[k * 64 + n]);
  }
}

// ---------------------------------------------------------------------------
// gemm1 fused: H1b[M,256](bf16) = x[M,256](f32) @ W1t^T, alpha1 in epilogue.
// BM=64, BN=256 (full width), BK=64; 4 waves (2 row x 2 col halves).
// Each head's 64 cols lie entirely within one wave's 128-col half ->
// per-(row,head) dot reduces with shfl_xor over the 16 l15 lanes, no atomics.
// ---------------------------------------------------------------------------

#define LDT2 72

__global__ __launch_bounds__(256) void gemm1_fused(const float* __restrict__ A,
                                                   const unsigned short* __restrict__ Bt,
                                                   unsigned short* __restrict__ C,
                                                   const float* __restrict__ a_src,
                                                   const float* __restrict__ a_dst,
                                                   float* __restrict__ asrc,
                                                   float* __restrict__ adst, int M) {
  const int K = 256;
  __shared__ unsigned short As[64 * LDT2];
  __shared__ unsigned short Bs[256 * LDT2];
  int bm = blockIdx.x * 64;
  int tid = threadIdx.x;
  int wid = tid >> 6, lane = tid & 63;
  int wr = (wid >> 1) * 32, wc = (wid & 1) * 128;
  int l15 = lane & 15, lq = lane >> 4;

  f32x4 acc[2][8];
  #pragma unroll
  for (int i = 0; i < 2; ++i)
    #pragma unroll
    for (int f = 0; f < 8; ++f) acc[i][f] = (f32x4){0,0,0,0};

  for (int k0 = 0; k0 < K; k0 += 64) {
    {   // stage A with f32->bf16 conversion (coalesced 64B/lane)
      int r = tid >> 2, c = (tid & 3) * 16;
      int row = bm + r;
      ushort4v o[4];
      #pragma unroll
      for (int p = 0; p < 4; ++p) {
        float4 v = make_float4(0.f, 0.f, 0.f, 0.f);
        if (row < M) v = *(const float4*)&A[(size_t)row * K + k0 + c + p * 4];
        o[p][0]=f2bf(v.x); o[p][1]=f2bf(v.y); o[p][2]=f2bf(v.z); o[p][3]=f2bf(v.w);
      }
      #pragma unroll
      for (int p = 0; p < 4; ++p)
        *(ushort4v*)&As[r * LDT2 + c + p * 4] = o[p];
    }
    #pragma unroll
    for (int p = 0; p < 4; ++p) {   // stage B (256 rows x 64 k)
      int r = p * 64 + (tid >> 2), seg = (tid & 3) * 16;
      ushort8 v0 = *(const ushort8*)&Bt[(size_t)r * K + k0 + seg];
      ushort8 v1 = *(const ushort8*)&Bt[(size_t)r * K + k0 + seg + 8];
      *(ushort8*)&Bs[r * LDT2 + seg]     = v0;
      *(ushort8*)&Bs[r * LDT2 + seg + 8] = v1;
    }
    __syncthreads();

    #pragma unroll
    for (int ks = 0; ks < 2; ++ks) {
      short8 a0 = *(const short8*)&As[(wr + l15) * LDT2 + ks * 32 + lq * 8];
      short8 a1 = *(const short8*)&As[(wr + 16 + l15) * LDT2 + ks * 32 + lq * 8];
      #pragma unroll
      for (int f = 0; f < 8; ++f) {
        short8 b = *(const short8*)&Bs[(wc + f * 16 + l15) * LDT2 + ks * 32 + lq * 8];
        acc[0][f] = __builtin_amdgcn_mfma_f32_16x16x32_bf16(a0, b, acc[0][f], 0, 0, 0);
        acc[1][f] = __builtin_amdgcn_mfma_f32_16x16x32_bf16(a1, b, acc[1][f], 0, 0, 0);
      }
    }
    __syncthreads();
  }

  // C store: col = lane&15 (+16f), row = (lane>>4)*4 + reg
  #pragma unroll
  for (int r = 0; r < 4; ++r) {
    int row0 = bm + wr + lq * 4 + r;
    int row1 = row0 + 16;
    #pragma unroll
    for (int f = 0; f < 8; ++f) {
      int col = wc + f * 16 + l15;
      if (row0 < M) C[(size_t)row0 * 256 + col] = f2bf(acc[0][f][r]);
      if (row1 < M) C[(size_t)row1 * 256 + col] = f2bf(acc[1][f][r]);
    }
  }

  // alpha epilogue: per-(row, head) dot with a_src/a_dst
  float ps[2][4][2], pd[2][4][2];
  #pragma unroll
  for (int i = 0; i < 2; ++i)
    #pragma unroll
    for (int r = 0; r < 4; ++r) { ps[i][r][0]=0.f; ps[i][r][1]=0.f; pd[i][r][0]=0.f; pd[i][r][1]=0.f; }
  #pragma unroll
  for (int f = 0; f < 8; ++f) {
    int col = wc + f * 16 + l15;
    float av = a_src[col], dv = a_dst[col];
    int hh = f >> 2;
    #pragma unroll
    for (int i = 0; i < 2; ++i)
      #pragma unroll
      for (int r = 0; r < 4; ++r) {
        ps[i][r][hh] += acc[i][f][r] * av;
        pd[i][r][hh] += acc[i][f][r] * dv;
      }
  }
  #pragma unroll
  for (int off = 1; off < 16; off <<= 1) {
    #pragma unroll
    for (int i = 0; i < 2; ++i)
      #pragma unroll
      for (int r = 0; r < 4; ++r) {
        ps[i][r][0] += __shfl_xor(ps[i][r][0], off);
        ps[i][r][1] += __shfl_xor(ps[i][r][1], off);
        pd[i][r][0] += __shfl_xor(pd[i][r][0], off);
        pd[i][r][1] += __shfl_xor(pd[i][r][1], off);
      }
  }
  if (l15 == 0) {
    int hb = wc >> 6;   // 0 or 2
    #pragma unroll
    for (int i = 0; i < 2; ++i)
      #pragma unroll
      for (int r = 0; r < 4; ++r) {
        int row = bm + wr + lq * 4 + r + i * 16;
        if (row < M) {
          asrc[row * 4 + hb]     = ps[i][r][0];
          asrc[row * 4 + hb + 1] = ps[i][r][1];
          adst[row * 4 + hb]     = pd[i][r][0];
          adst[row * 4 + hb + 1] = pd[i][r][1];
        }
      }
  }
}

// ---------------------------------------------------------------------------
// gemm2 fused: H2b[M,64](bf16) = X2b[M,256](bf16) @ W2t^T, alpha2 in epilogue.
// BM=64, BN=64, BK=64; alpha2 spans both col-halves -> LDS combine.
// ---------------------------------------------------------------------------

__global__ __launch_bounds__(256) void gemm2_fused(const unsigned short* __restrict__ A,
                                                   const unsigned short* __restrict__ Bt,
                                                   unsigned short* __restrict__ C,
                                                   const float* __restrict__ a_src,
                                                   const float* __restrict__ a_dst,
                                                   float* __restrict__ asrc,
                                                   float* __restrict__ adst, int M) {
  const int K = 256;
  __shared__ unsigned short As[64 * LDT2];
  __shared__ unsigned short Bs[64 * LDT2];
  __shared__ float sred[64], dred[64];
  int bm = blockIdx.x * 64;
  int tid = threadIdx.x;
  int wid = tid >> 6, lane = tid & 63;
  int wr = (wid >> 1) * 32, wc = (wid & 1) * 32;
  int l15 = lane & 15, lq = lane >> 4;

  f32x4 acc[2][2];
  #pragma unroll
  for (int i = 0; i < 2; ++i) { acc[i][0] = (f32x4){0,0,0,0}; acc[i][1] = (f32x4){0,0,0,0}; }

  for (int k0 = 0; k0 < K; k0 += 64) {
    {
      int r = tid >> 2, seg = (tid & 3) * 16;
      int row = bm + r;
      ushort8 v0 = {0,0,0,0,0,0,0,0}, v1 = {0,0,0,0,0,0,0,0};
      if (row < M) {
        v0 = *(const ushort8*)&A[(size_t)row * K + k0 + seg];
        v1 = *(const ushort8*)&A[(size_t)row * K + k0 + seg + 8];
      }
      *(ushort8*)&As[r * LDT2 + seg]     = v0;
      *(ushort8*)&As[r * LDT2 + seg + 8] = v1;
    }
    {
      int r = tid >> 2, seg = (tid & 3) * 16;
      ushort8 v0 = *(const ushort8*)&Bt[(size_t)r * K + k0 + seg];
      ushort8 v1 = *(const ushort8*)&Bt[(size_t)r * K + k0 + seg + 8];
      *(ushort8*)&Bs[r * LDT2 + seg]     = v0;
      *(ushort8*)&Bs[r * LDT2 + seg + 8] = v1;
    }
    __syncthreads();

    #pragma unroll
    for (int ks = 0; ks < 2; ++ks) {
      short8 a0 = *(const short8*)&As[(wr + l15) * LDT2 + ks * 32 + lq * 8];
      short8 a1 = *(const short8*)&As[(wr + 16 + l15) * LDT2 + ks * 32 + lq * 8];
      #pragma unroll
      for (int f = 0; f < 2; ++f) {
        short8 b = *(const short8*)&Bs[(wc + f * 16 + l15) * LDT2 + ks * 32 + lq * 8];
        acc[0][f] = __builtin_amdgcn_mfma_f32_16x16x32_bf16(a0, b, acc[0][f], 0, 0, 0);
        acc[1][f] = __builtin_amdgcn_mfma_f32_16x16x32_bf16(a1, b, acc[1][f], 0, 0, 0);
      }
    }
    __syncthreads();
  }

  #pragma unroll
  for (int r = 0; r < 4; ++r) {
    int row0 = bm + wr + lq * 4 + r;
    int row1 = row0 + 16;
    #pragma unroll
    for (int f = 0; f < 2; ++f) {
      int col = wc + f * 16 + l15;
      if (row0 < M) C[(size_t)row0 * 64 + col] = f2bf(acc[0][f][r]);
      if (row1 < M) C[(size_t)row1 * 64 + col] = f2bf(acc[1][f][r]);
    }
  }

  // alpha2 epilogue
  float ps[2][4], pd[2][4];
  #pragma unroll
  for (int i = 0; i < 2; ++i)
    #pragma unroll
    for (int r = 0; r < 4; ++r) { ps[i][r] = 0.f; pd[i][r] = 0.f; }
  #pragma unroll
  for (int f = 0; f < 2; ++f) {
    int col = wc + f * 16 + l15;
    float av = a_src[col], dv = a_dst[col];
    #pragma unroll
    for (int i = 0; i < 2; ++i)
      #pragma unroll
      for (int r = 0; r < 4; ++r) {
        ps[i][r] += acc[i][f][r] * av;
        pd[i][r] += acc[i][f][r] * dv;
      }
  }
  #pragma unroll
  for (int off = 1; off < 16; off <<= 1) {
    #pragma unroll
    for (int i = 0; i < 2; ++i)
      #pragma unroll
      for (int r = 0; r < 4; ++r) {
        ps[i][r] += __shfl_xor(ps[i][r], off);
        pd[i][r] += __shfl_xor(pd[i][r], off);
      }
  }
  if ((wid & 1) == 0 && l15 == 0) {
    #pragma unroll
    for (int i = 0; i < 2; ++i)
      #pragma unroll
      for (int r = 0; r < 4; ++r) {
        int rl = wr + lq * 4 + r + i * 16;
        sred[rl] = ps[i][r];
        dred[rl] = pd[i][r];
      }
  }
  __syncthreads();
  if ((wid & 1) == 1 && l15 == 0) {
    #pragma unroll
    for (int i = 0; i < 2; ++i)
      #pragma unroll
      for (int r = 0; r < 4; ++r) {
        int rl = wr + lq * 4 + r + i * 16;
        int row = bm + rl;
        if (row < M) {
          asrc[row] = sred[rl] + ps[i][r];
          adst[row] = dred[rl] + pd[i][r];
        }
      }
  }
}

// ---------------------------------------------------------------------------
// Layer-2 edge weights, dst-major (wave per node)
// ---------------------------------------------------------------------------

__global__ __launch_bounds__(256) void edgew2_kernel(const int* __restrict__ indptr,
                                                     const int* __restrict__ srcs,
                                                     const float* __restrict__ asrc,
                                                     const float* __restrict__ adst,
                                                     float* __restrict__ w, int N) {
  int n = blockIdx.x * 4 + (threadIdx.x >> 6);
  if (n >= N) return;
  int lane = threadIdx.x & 63;
  int start = indptr[n], end = indptr[n + 1];
  float ad = adst[n];
  for (int k = start + lane; k < end; k += 64) {
    float e = asrc[srcs[k]] + ad;
    e = (e > 0.f) ? e : 0.2f * e;
    w[k] = __expf(e);
  }
}

// ---------------------------------------------------------------------------
// GAT agg layer 1: wave per node, split-wave (2 edges), 16B/lane, 2x unroll.
// ---------------------------------------------------------------------------

__global__ __launch_bounds__(256) void gat1_agg(const unsigned short* __restrict__ H1b,
                                                const float* __restrict__ w,
                                                const int* __restrict__ indptr,
                                                const int* __restrict__ srcs,
                                                const float* __restrict__ b1,
                                                const float* __restrict__ g1,
                                                const float* __restrict__ be1,
                                                const float* __restrict__ mu1,
                                                const float* __restrict__ var1,
                                                unsigned short* __restrict__ X2b, int N) {
  int n = blockIdx.x * 4 + (threadIdx.x >> 6);
  if (n >= N) return;
  int lane = threadIdx.x & 63;
  int half = lane >> 5;
  int j = lane & 31;
  int h = j >> 3;
  int start = indptr[n], end = indptr[n + 1];

  float acc[8] = {0.f,0.f,0.f,0.f,0.f,0.f,0.f,0.f};
  float wsum = 0.f;
  int k = start + half;
  for (; k + 2 < end; k += 4) {
    int s0 = srcs[k], s1 = srcs[k + 2];
    float w0 = w[k * 4 + h], w1v = w[(k + 2) * 4 + h];
    ushort8 r0 = *(const ushort8*)&H1b[(size_t)s0 * C1 + j * 8];
    ushort8 r1 = *(const ushort8*)&H1b[(size_t)s1 * C1 + j * 8];
    wsum += w0 + w1v;
    #pragma unroll
    for (int i = 0; i < 8; ++i)
      acc[i] += w0 * bf2f(r0[i]) + w1v * bf2f(r1[i]);
  }
  for (; k < end; k += 2) {
    int s0 = srcs[k];
    float w0 = w[k * 4 + h];
    ushort8 r0 = *(const ushort8*)&H1b[(size_t)s0 * C1 + j * 8];
    wsum += w0;
    #pragma unroll
    for (int i = 0; i < 8; ++i) acc[i] += w0 * bf2f(r0[i]);
  }
  #pragma unroll
  for (int i = 0; i < 8; ++i) acc[i] += __shfl_xor(acc[i], 32);
  wsum += __shfl_xor(wsum, 32);

  if (half == 0) {
    float inv = 1.f / (wsum + 1e-16f);
    int f = j * 8;
    ushort8 o;
    #pragma unroll
    for (int i = 0; i < 8; ++i) {
      float val = (acc[i] * inv + b1[f + i] - mu1[f + i]) *
                  (g1[f + i] * rsqrtf(var1[f + i] + 1e-5f)) + be1[f + i];
      val = (val > 0.f) ? val : (__expf(val) - 1.f);
      o[i] = f2bf(val);
    }
    *(ushort8*)&X2b[(size_t)n * C1 + f] = o;
  }
}

// ---------------------------------------------------------------------------
// GAT agg layer 2: wave per node, 8 edge slots, 16B/lane features.
// ---------------------------------------------------------------------------

__global__ __launch_bounds__(256) void gat2_agg(const unsigned short* __restrict__ H2b,
                                                const float* __restrict__ w,
                                                const int* __restrict__ indptr,
                                                const int* __restrict__ srcs,
                                                const float* __restrict__ b2,
                                                const float* __restrict__ g2,
                                                const float* __restrict__ be2,
                                                const float* __restrict__ mu2,
                                                const float* __restrict__ var2,
                                                float* __restrict__ out, int N) {
  int n = blockIdx.x * 4 + (threadIdx.x >> 6);
  if (n >= N) return;
  int lane = threadIdx.x & 63;
  int q = lane >> 3;
  int j = lane & 7;
  int start = indptr[n], end = indptr[n + 1];

  float acc[8];
  #pragma unroll
  for (int i = 0; i < 8; ++i) acc[i] = 0.f;
  float wsum = 0.f;

  for (int k = start + q; k < end; k += 8) {
    int s = srcs[k];
    float wt = w[k];
    ushort8 raw = *(const ushort8*)&H2b[(size_t)s * HID + j * 8];
    wsum += wt;
    #pragma unroll
    for (int i = 0; i < 8; ++i) acc[i] += wt * bf2f(raw[i]);
  }
  #pragma unroll
  for (int i = 0; i < 8; ++i) {
    acc[i] += __shfl_xor(acc[i], 8);
    acc[i] += __shfl_xor(acc[i], 16);
    acc[i] += __shfl_xor(acc[i], 32);
  }
  wsum += __shfl_xor(wsum, 8);
  wsum += __shfl_xor(wsum, 16);
  wsum += __shfl_xor(wsum, 32);

  if (q == 0) {
    float inv = 1.f / (wsum + 1e-16f);
    int f = j * 8;
    float o[8];
    #pragma unroll
    for (int i = 0; i < 8; ++i) {
      float val = (acc[i] * inv + b2[f + i] - mu2[f + i]) *
                  (g2[f + i] * rsqrtf(var2[f + i] + 1e-5f)) + be2[f + i];
      o[i] = (val > 0.f) ? val : (__expf(val) - 1.f);
    }
    *(float4*)&out[(size_t)n * HID + f]     = make_float4(o[0], o[1], o[2], o[3]);
    *(float4*)&out[(size_t)n * HID + f + 4] = make_float4(o[4], o[5], o[6], o[7]);
  }
}

// ---------------------------------------------------------------------------

extern "C" void kernel_launch(void* const* d_in, const int* in_sizes, int n_in,
                              void* d_out, int out_size, void* d_ws, size_t ws_size,
                              hipStream_t stream) {
  const float* x      = (const float*)d_in[0];
  const int*   ei     = (const int*)d_in[1];
  const float* W1     = (const float*)d_in[2];
  const float* a_src1 = (const float*)d_in[3];
  const float* a_dst1 = (const float*)d_in[4];
  const float* b1     = (const float*)d_in[5];
  const float* g1     = (const float*)d_in[6];
  const float* be1    = (const float*)d_in[7];
  const float* mu1    = (const float*)d_in[8];
  const float* var1   = (const float*)d_in[9];
  const float* W2     = (const float*)d_in[10];
  const float* a_src2 = (const float*)d_in[11];
  const float* a_dst2 = (const float*)d_in[12];
  const float* b2     = (const float*)d_in[13];
  const float* g2     = (const float*)d_in[14];
  const float* be2    = (const float*)d_in[15];
  const float* mu2    = (const float*)d_in[16];
  const float* var2   = (const float*)d_in[17];
  float* out = (float*)d_out;

  int N = in_sizes[0] / IN_DIM;
  int E = in_sizes[1] / 2;
  int Etot = E + N;
  int NB = (N + 1023) / 1024;

  // Workspace (~72 MB):
  //   H1b[N*256]b (reused H2b) | X2b[N*256]b | W1t[256*256]b | W2t[64*256]b |
  //   w1[4*Etot]f (reused w2) | asrc1[4N]f | adst1[4N]f | asrc2[N]f |
  //   adst2[N]f | counts[N] | indptr[N+1] | fillpos[N] | blocksums[NB] |
  //   blockoff[NB+1] | srcs[Etot]
  unsigned short* H1b = (unsigned short*)d_ws;
  unsigned short* X2b = H1b + (size_t)N * C1;
  unsigned short* W1t = X2b + (size_t)N * C1;
  unsigned short* W2t = W1t + 256 * 256;
  float* w1    = (float*)(W2t + 64 * 256);
  float* asrc1 = w1 + (size_t)4 * Etot;
  float* adst1 = asrc1 + (size_t)N * HEADS;
  float* asrc2 = adst1 + (size_t)N * HEADS;
  float* adst2 = asrc2 + N;
  int* counts    = (int*)(adst2 + N);
  int* indptr    = counts + N;
  int* fillpos   = indptr + (N + 1);
  int* blocksums = fillpos + N;
  int* blockoff  = blocksums + NB;
  int* srcs      = blockoff + (NB + 1);
  unsigned short* H2b = H1b;   // H1b dead after gat1_agg
  float* w2 = w1;              // w1 dead before edgew2

  // --- CSR prep (indptr/fillpos) + weight transposes ---
  convw_kernel<<<(256 * 256 + 64 * 256 + 255) / 256, 256, 0, stream>>>(W1, W1t, W2, W2t);
  zero_int_kernel<<<(N + 255) / 256, 256, 0, stream>>>(counts, N);
  hist_kernel<<<(Etot + 255) / 256, 256, 0, stream>>>(ei, E, N, counts);
  scan1_kernel<<<NB, 256, 0, stream>>>(counts, blocksums, N);
  scan2_kernel<<<1, 64, 0, stream>>>(blocksums, blockoff, NB);
  scan3_kernel<<<NB, 256, 0, stream>>>(counts, blockoff, indptr, fillpos, N);

  // --- Layer 1 ---
  gemm1_fused<<<(N + 63) / 64, 256, 0, stream>>>(x, W1t, H1b, a_src1, a_dst1,
                                                 asrc1, adst1, N);
  fillw_kernel<<<(Etot + 255) / 256, 256, 0, stream>>>(ei, E, N, fillpos, srcs,
                                                       asrc1, adst1, w1);
  gat1_agg<<<(N + 3) / 4, 256, 0, stream>>>(H1b, w1, indptr, srcs,
                                            b1, g1, be1, mu1, var1, X2b, N);

  // --- Layer 2 ---
  gemm2_fused<<<(N + 63) / 64, 256, 0, stream>>>(X2b, W2t, H2b, a_src2, a_dst2,
                                                 asrc2, adst2, N);
  edgew2_kernel<<<(N + 3) / 4, 256, 0, stream>>>(indptr, srcs, asrc2, adst2, w2, N);
  gat2_agg<<<(N + 3) / 4, 256, 0, stream>>>(H2b, w2, indptr, srcs,
                                            b2, g2, be2, mu2, var2, out, N);
}

// Round 11
// 243.557 us; speedup vs baseline: 1.1755x; 1.0115x over previous
//
#include <hip/hip_runtime.h>

#define IN_DIM 256
#define HID 64
#define HEADS 4
#define C1 256   // HID*HEADS

typedef __attribute__((ext_vector_type(4))) float  f32x4;
typedef __attribute__((ext_vector_type(8))) short  short8;
typedef __attribute__((ext_vector_type(8))) unsigned short ushort8;
typedef __attribute__((ext_vector_type(4))) unsigned short ushort4v;

static __device__ __forceinline__ unsigned short f2bf(float f) {
  union { float f; unsigned int u; } v; v.f = f;
  unsigned int r = v.u + 0x7fffu + ((v.u >> 16) & 1u);   // RNE
  return (unsigned short)(r >> 16);
}
static __device__ __forceinline__ float bf2f(unsigned short u) {
  union { unsigned int u; float f; } v; v.u = ((unsigned int)u) << 16;
  return v.f;
}

// ---------------------------------------------------------------------------
// prep: weight transposes (f32 -> bf16, [k][n] -> [n][k]) + zero counts/done
// ---------------------------------------------------------------------------

__global__ __launch_bounds__(256) void prep_kernel(const float* __restrict__ W1,
                                                   unsigned short* __restrict__ W1t,
                                                   const float* __restrict__ W2,
                                                   unsigned short* __restrict__ W2t,
                                                   int* __restrict__ counts,
                                                   int* __restrict__ done, int N) {
  int t = blockIdx.x * 256 + threadIdx.x;
  if (t == 0) *done = 0;
  if (t < 256 * 256) {
    int k = t & 255, n = t >> 8;
    W1t[n * 256 + k] = f2bf(W1[k * 256 + n]);
  } else if (t < 256 * 256 + 64 * 256) {
    int u = t - 256 * 256;
    int k = u & 255, n = u >> 8;
    W2t[n * 256 + k] = f2bf(W2[k * 64 + n]);
  } else {
    int i = t - (256 * 256 + 64 * 256);
    if (i < N) counts[i] = 0;
  }
}

// ---------------------------------------------------------------------------
// CSR build
// ---------------------------------------------------------------------------

__global__ __launch_bounds__(256) void hist_kernel(const int* __restrict__ ei,
                                                   int E, int N, int* __restrict__ counts) {
  int e = blockIdx.x * 256 + threadIdx.x;
  if (e >= E + N) return;
  int dst = (e < E) ? ei[(size_t)E + e] : (e - E);
  atomicAdd(&counts[dst], 1);
}

// scan1 + scan2 fused: per-block sums, last-finishing block scans block sums.
__global__ __launch_bounds__(256) void scan12_kernel(const int* __restrict__ counts,
                                                     int* __restrict__ blocksums,
                                                     int* __restrict__ blockoff,
                                                     int* __restrict__ done,
                                                     int N, int NB) {
  int tid = threadIdx.x;
  int base = blockIdx.x * 1024 + tid * 4;
  int s = 0;
  if (base + 3 < N) {
    int4 v = *(const int4*)&counts[base];
    s = v.x + v.y + v.z + v.w;
  } else {
    for (int i = 0; i < 4; ++i) if (base + i < N) s += counts[base + i];
  }
  __shared__ int red[256];
  red[tid] = s;
  __syncthreads();
  for (int off = 128; off; off >>= 1) {
    if (tid < off) red[tid] += red[tid + off];
    __syncthreads();
  }
  __shared__ int amLast;
  if (tid == 0) {
    blocksums[blockIdx.x] = red[0];
    __threadfence();
    amLast = (atomicAdd(done, 1) == NB - 1);
  }
  __syncthreads();
  if (amLast && tid < 64) {
    __threadfence();   // acquire: make all blocksums visible
    int lane = tid;
    int carry = 0;
    for (int b = 0; b < NB; b += 64) {
      int v = (b + lane < NB) ? blocksums[b + lane] : 0;
      int incl = v;
      #pragma unroll
      for (int off = 1; off < 64; off <<= 1) {
        int t = __shfl_up(incl, off);
        if (lane >= off) incl += t;
      }
      if (b + lane < NB) blockoff[b + lane] = carry + incl - v;
      carry += __shfl(incl, 63);
    }
    if (lane == 0) blockoff[NB] = carry;
  }
}

__global__ __launch_bounds__(256) void scan3_kernel(const int* __restrict__ counts,
                                                    const int* __restrict__ blockoff,
                                                    int* __restrict__ indptr,
                                                    int* __restrict__ fillpos, int N, int NB) {
  int tid = threadIdx.x;
  int base = blockIdx.x * 1024 + tid * 4;
  int c0 = 0, c1 = 0, c2 = 0, c3 = 0;
  if (base + 3 < N) {
    int4 v = *(const int4*)&counts[base];
    c0 = v.x; c1 = v.y; c2 = v.z; c3 = v.w;
  } else {
    if (base + 0 < N) c0 = counts[base + 0];
    if (base + 1 < N) c1 = counts[base + 1];
    if (base + 2 < N) c2 = counts[base + 2];
    if (base + 3 < N) c3 = counts[base + 3];
  }
  int s = c0 + c1 + c2 + c3;
  __shared__ int sc[256];
  sc[tid] = s;
  __syncthreads();
  for (int off = 1; off < 256; off <<= 1) {
    int t = (tid >= off) ? sc[tid - off] : 0;
    __syncthreads();
    sc[tid] += t;
    __syncthreads();
  }
  int p = sc[tid] - s + blockoff[blockIdx.x];
  if (base + 0 < N) { indptr[base + 0] = p; fillpos[base + 0] = p; p += c0; }
  if (base + 1 < N) { indptr[base + 1] = p; fillpos[base + 1] = p; p += c1; }
  if (base + 2 < N) { indptr[base + 2] = p; fillpos[base + 2] = p; p += c2; }
  if (base + 3 < N) { indptr[base + 3] = p; fillpos[base + 3] = p; p += c3; }
  if (blockIdx.x == 0 && tid == 0) indptr[N] = blockoff[NB];
}

// fill fused with layer-1 edge weights.
__global__ __launch_bounds__(256) void fillw_kernel(const int* __restrict__ ei, int E, int N,
                                                    int* __restrict__ fillpos,
                                                    int* __restrict__ srcs,
                                                    const float* __restrict__ asrc,
                                                    const float* __restrict__ adst,
                                                    float* __restrict__ w) {
  int e = blockIdx.x * 256 + threadIdx.x;
  if (e >= E + N) return;
  int src, dst;
  if (e < E) { src = ei[e]; dst = ei[(size_t)E + e]; }
  else       { src = e - E; dst = e - E; }
  int pos = atomicAdd(&fillpos[dst], 1);
  srcs[pos] = src;
  float4 as = *(const float4*)&asrc[src * 4];
  float4 ad = *(const float4*)&adst[dst * 4];
  float e0 = as.x + ad.x; e0 = (e0 > 0.f) ? e0 : 0.2f * e0;
  float e1 = as.y + ad.y; e1 = (e1 > 0.f) ? e1 : 0.2f * e1;
  float e2 = as.z + ad.z; e2 = (e2 > 0.f) ? e2 : 0.2f * e2;
  float e3 = as.w + ad.w; e3 = (e3 > 0.f) ? e3 : 0.2f * e3;
  *(float4*)&w[pos * 4] = make_float4(__expf(e0), __expf(e1), __expf(e2), __expf(e3));
}

// ---------------------------------------------------------------------------
// gemm1 fused: H1b[M,256](bf16) = x[M,256](f32) @ W1t^T, alpha1 in epilogue.
// BM=128, BN=256, BK=64; 512 threads = 8 waves (4 row x 2 col halves).
// ---------------------------------------------------------------------------

#define LDT2 72

__global__ __launch_bounds__(512) void gemm1_fused(const float* __restrict__ A,
                                                   const unsigned short* __restrict__ Bt,
                                                   unsigned short* __restrict__ C,
                                                   const float* __restrict__ a_src,
                                                   const float* __restrict__ a_dst,
                                                   float* __restrict__ asrc,
                                                   float* __restrict__ adst, int M) {
  const int K = 256;
  __shared__ unsigned short As[128 * LDT2];
  __shared__ unsigned short Bs[256 * LDT2];
  int bm = blockIdx.x * 128;
  int tid = threadIdx.x;
  int wid = tid >> 6, lane = tid & 63;
  int wr = (wid >> 1) * 32, wc = (wid & 1) * 128;
  int l15 = lane & 15, lq = lane >> 4;

  f32x4 acc[2][8];
  #pragma unroll
  for (int i = 0; i < 2; ++i)
    #pragma unroll
    for (int f = 0; f < 8; ++f) acc[i][f] = (f32x4){0,0,0,0};

  for (int k0 = 0; k0 < K; k0 += 64) {
    {   // stage A (128 rows x 64 k) with f32->bf16 conversion, 64B/lane
      int r = tid >> 2, c = (tid & 3) * 16;
      int row = bm + r;
      ushort4v o[4];
      #pragma unroll
      for (int p = 0; p < 4; ++p) {
        float4 v = make_float4(0.f, 0.f, 0.f, 0.f);
        if (row < M) v = *(const float4*)&A[(size_t)row * K + k0 + c + p * 4];
        o[p][0]=f2bf(v.x); o[p][1]=f2bf(v.y); o[p][2]=f2bf(v.z); o[p][3]=f2bf(v.w);
      }
      #pragma unroll
      for (int p = 0; p < 4; ++p)
        *(ushort4v*)&As[r * LDT2 + c + p * 4] = o[p];
    }
    #pragma unroll
    for (int p = 0; p < 2; ++p) {   // stage B (256 rows x 64 k)
      int r = p * 128 + (tid >> 2), seg = (tid & 3) * 16;
      ushort8 v0 = *(const ushort8*)&Bt[(size_t)r * K + k0 + seg];
      ushort8 v1 = *(const ushort8*)&Bt[(size_t)r * K + k0 + seg + 8];
      *(ushort8*)&Bs[r * LDT2 + seg]     = v0;
      *(ushort8*)&Bs[r * LDT2 + seg + 8] = v1;
    }
    __syncthreads();

    #pragma unroll
    for (int ks = 0; ks < 2; ++ks) {
      short8 a0 = *(const short8*)&As[(wr + l15) * LDT2 + ks * 32 + lq * 8];
      short8 a1 = *(const short8*)&As[(wr + 16 + l15) * LDT2 + ks * 32 + lq * 8];
      #pragma unroll
      for (int f = 0; f < 8; ++f) {
        short8 b = *(const short8*)&Bs[(wc + f * 16 + l15) * LDT2 + ks * 32 + lq * 8];
        acc[0][f] = __builtin_amdgcn_mfma_f32_16x16x32_bf16(a0, b, acc[0][f], 0, 0, 0);
        acc[1][f] = __builtin_amdgcn_mfma_f32_16x16x32_bf16(a1, b, acc[1][f], 0, 0, 0);
      }
    }
    __syncthreads();
  }

  // C store: col = lane&15 (+16f), row = (lane>>4)*4 + reg
  #pragma unroll
  for (int r = 0; r < 4; ++r) {
    int row0 = bm + wr + lq * 4 + r;
    int row1 = row0 + 16;
    #pragma unroll
    for (int f = 0; f < 8; ++f) {
      int col = wc + f * 16 + l15;
      if (row0 < M) C[(size_t)row0 * 256 + col] = f2bf(acc[0][f][r]);
      if (row1 < M) C[(size_t)row1 * 256 + col] = f2bf(acc[1][f][r]);
    }
  }

  // alpha epilogue: per-(row, head) dot with a_src/a_dst
  float ps[2][4][2], pd[2][4][2];
  #pragma unroll
  for (int i = 0; i < 2; ++i)
    #pragma unroll
    for (int r = 0; r < 4; ++r) { ps[i][r][0]=0.f; ps[i][r][1]=0.f; pd[i][r][0]=0.f; pd[i][r][1]=0.f; }
  #pragma unroll
  for (int f = 0; f < 8; ++f) {
    int col = wc + f * 16 + l15;
    float av = a_src[col], dv = a_dst[col];
    int hh = f >> 2;
    #pragma unroll
    for (int i = 0; i < 2; ++i)
      #pragma unroll
      for (int r = 0; r < 4; ++r) {
        ps[i][r][hh] += acc[i][f][r] * av;
        pd[i][r][hh] += acc[i][f][r] * dv;
      }
  }
  #pragma unroll
  for (int off = 1; off < 16; off <<= 1) {
    #pragma unroll
    for (int i = 0; i < 2; ++i)
      #pragma unroll
      for (int r = 0; r < 4; ++r) {
        ps[i][r][0] += __shfl_xor(ps[i][r][0], off);
        ps[i][r][1] += __shfl_xor(ps[i][r][1], off);
        pd[i][r][0] += __shfl_xor(pd[i][r][0], off);
        pd[i][r][1] += __shfl_xor(pd[i][r][1], off);
      }
  }
  if (l15 == 0) {
    int hb = wc >> 6;   // 0 or 2
    #pragma unroll
    for (int i = 0; i < 2; ++i)
      #pragma unroll
      for (int r = 0; r < 4; ++r) {
        int row = bm + wr + lq * 4 + r + i * 16;
        if (row < M) {
          asrc[row * 4 + hb]     = ps[i][r][0];
          asrc[row * 4 + hb + 1] = ps[i][r][1];
          adst[row * 4 + hb]     = pd[i][r][0];
          adst[row * 4 + hb + 1] = pd[i][r][1];
        }
      }
  }
}

// ---------------------------------------------------------------------------
// gemm2 fused: H2b[M,64](bf16) = X2b[M,256](bf16) @ W2t^T, alpha2 in epilogue.
// ---------------------------------------------------------------------------

__global__ __launch_bounds__(256) void gemm2_fused(const unsigned short* __restrict__ A,
                                                   const unsigned short* __restrict__ Bt,
                                                   unsigned short* __restrict__ C,
                                                   const float* __restrict__ a_src,
                                                   const float* __restrict__ a_dst,
                                                   float* __restrict__ asrc,
                                                   float* __restrict__ adst, int M) {
  const int K = 256;
  __shared__ unsigned short As[64 * LDT2];
  __shared__ unsigned short Bs[64 * LDT2];
  __shared__ float sred[64], dred[64];
  int bm = blockIdx.x * 64;
  int tid = threadIdx.x;
  int wid = tid >> 6, lane = tid & 63;
  int wr = (wid >> 1) * 32, wc = (wid & 1) * 32;
  int l15 = lane & 15, lq = lane >> 4;

  f32x4 acc[2][2];
  #pragma unroll
  for (int i = 0; i < 2; ++i) { acc[i][0] = (f32x4){0,0,0,0}; acc[i][1] = (f32x4){0,0,0,0}; }

  for (int k0 = 0; k0 < K; k0 += 64) {
    {
      int r = tid >> 2, seg = (tid & 3) * 16;
      int row = bm + r;
      ushort8 v0 = {0,0,0,0,0,0,0,0}, v1 = {0,0,0,0,0,0,0,0};
      if (row < M) {
        v0 = *(const ushort8*)&A[(size_t)row * K + k0 + seg];
        v1 = *(const ushort8*)&A[(size_t)row * K + k0 + seg + 8];
      }
      *(ushort8*)&As[r * LDT2 + seg]     = v0;
      *(ushort8*)&As[r * LDT2 + seg + 8] = v1;
    }
    {
      int r = tid >> 2, seg = (tid & 3) * 16;
      ushort8 v0 = *(const ushort8*)&Bt[(size_t)r * K + k0 + seg];
      ushort8 v1 = *(const ushort8*)&Bt[(size_t)r * K + k0 + seg + 8];
      *(ushort8*)&Bs[r * LDT2 + seg]     = v0;
      *(ushort8*)&Bs[r * LDT2 + seg + 8] = v1;
    }
    __syncthreads();

    #pragma unroll
    for (int ks = 0; ks < 2; ++ks) {
      short8 a0 = *(const short8*)&As[(wr + l15) * LDT2 + ks * 32 + lq * 8];
      short8 a1 = *(const short8*)&As[(wr + 16 + l15) * LDT2 + ks * 32 + lq * 8];
      #pragma unroll
      for (int f = 0; f < 2; ++f) {
        short8 b = *(const short8*)&Bs[(wc + f * 16 + l15) * LDT2 + ks * 32 + lq * 8];
        acc[0][f] = __builtin_amdgcn_mfma_f32_16x16x32_bf16(a0, b, acc[0][f], 0, 0, 0);
        acc[1][f] = __builtin_amdgcn_mfma_f32_16x16x32_bf16(a1, b, acc[1][f], 0, 0, 0);
      }
    }
    __syncthreads();
  }

  #pragma unroll
  for (int r = 0; r < 4; ++r) {
    int row0 = bm + wr + lq * 4 + r;
    int row1 = row0 + 16;
    #pragma unroll
    for (int f = 0; f < 2; ++f) {
      int col = wc + f * 16 + l15;
      if (row0 < M) C[(size_t)row0 * 64 + col] = f2bf(acc[0][f][r]);
      if (row1 < M) C[(size_t)row1 * 64 + col] = f2bf(acc[1][f][r]);
    }
  }

  // alpha2 epilogue
  float ps[2][4], pd[2][4];
  #pragma unroll
  for (int i = 0; i < 2; ++i)
    #pragma unroll
    for (int r = 0; r < 4; ++r) { ps[i][r] = 0.f; pd[i][r] = 0.f; }
  #pragma unroll
  for (int f = 0; f < 2; ++f) {
    int col = wc + f * 16 + l15;
    float av = a_src[col], dv = a_dst[col];
    #pragma unroll
    for (int i = 0; i < 2; ++i)
      #pragma unroll
      for (int r = 0; r < 4; ++r) {
        ps[i][r] += acc[i][f][r] * av;
        pd[i][r] += acc[i][f][r] * dv;
      }
  }
  #pragma unroll
  for (int off = 1; off < 16; off <<= 1) {
    #pragma unroll
    for (int i = 0; i < 2; ++i)
      #pragma unroll
      for (int r = 0; r < 4; ++r) {
        ps[i][r] += __shfl_xor(ps[i][r], off);
        pd[i][r] += __shfl_xor(pd[i][r], off);
      }
  }
  if ((wid & 1) == 0 && l15 == 0) {
    #pragma unroll
    for (int i = 0; i < 2; ++i)
      #pragma unroll
      for (int r = 0; r < 4; ++r) {
        int rl = wr + lq * 4 + r + i * 16;
        sred[rl] = ps[i][r];
        dred[rl] = pd[i][r];
      }
  }
  __syncthreads();
  if ((wid & 1) == 1 && l15 == 0) {
    #pragma unroll
    for (int i = 0; i < 2; ++i)
      #pragma unroll
      for (int r = 0; r < 4; ++r) {
        int rl = wr + lq * 4 + r + i * 16;
        int row = bm + rl;
        if (row < M) {
          asrc[row] = sred[rl] + ps[i][r];
          adst[row] = dred[rl] + pd[i][r];
        }
      }
  }
}

// ---------------------------------------------------------------------------
// Layer-2 edge weights, dst-major (wave per node)
// ---------------------------------------------------------------------------

__global__ __launch_bounds__(256) void edgew2_kernel(const int* __restrict__ indptr,
                                                     const int* __restrict__ srcs,
                                                     const float* __restrict__ asrc,
                                                     const float* __restrict__ adst,
                                                     float* __restrict__ w, int N) {
  int n = blockIdx.x * 4 + (threadIdx.x >> 6);
  if (n >= N) return;
  int lane = threadIdx.x & 63;
  int start = indptr[n], end = indptr[n + 1];
  float ad = adst[n];
  for (int k = start + lane; k < end; k += 64) {
    float e = asrc[srcs[k]] + ad;
    e = (e > 0.f) ? e : 0.2f * e;
    w[k] = __expf(e);
  }
}

// ---------------------------------------------------------------------------
// GAT agg layer 1: wave per node, split-wave (2 edges), 16B/lane, 2x unroll.
// ---------------------------------------------------------------------------

__global__ __launch_bounds__(256) void gat1_agg(const unsigned short* __restrict__ H1b,
                                                const float* __restrict__ w,
                                                const int* __restrict__ indptr,
                                                const int* __restrict__ srcs,
                                                const float* __restrict__ b1,
                                                const float* __restrict__ g1,
                                                const float* __restrict__ be1,
                                                const float* __restrict__ mu1,
                                                const float* __restrict__ var1,
                                                unsigned short* __restrict__ X2b, int N) {
  int n = blockIdx.x * 4 + (threadIdx.x >> 6);
  if (n >= N) return;
  int lane = threadIdx.x & 63;
  int half = lane >> 5;
  int j = lane & 31;
  int h = j >> 3;
  int start = indptr[n], end = indptr[n + 1];

  float acc[8] = {0.f,0.f,0.f,0.f,0.f,0.f,0.f,0.f};
  float wsum = 0.f;
  int k = start + half;
  for (; k + 2 < end; k += 4) {
    int s0 = srcs[k], s1 = srcs[k + 2];
    float w0 = w[k * 4 + h], w1v = w[(k + 2) * 4 + h];
    ushort8 r0 = *(const ushort8*)&H1b[(size_t)s0 * C1 + j * 8];
    ushort8 r1 = *(const ushort8*)&H1b[(size_t)s1 * C1 + j * 8];
    wsum += w0 + w1v;
    #pragma unroll
    for (int i = 0; i < 8; ++i)
      acc[i] += w0 * bf2f(r0[i]) + w1v * bf2f(r1[i]);
  }
  for (; k < end; k += 2) {
    int s0 = srcs[k];
    float w0 = w[k * 4 + h];
    ushort8 r0 = *(const ushort8*)&H1b[(size_t)s0 * C1 + j * 8];
    wsum += w0;
    #pragma unroll
    for (int i = 0; i < 8; ++i) acc[i] += w0 * bf2f(r0[i]);
  }
  #pragma unroll
  for (int i = 0; i < 8; ++i) acc[i] += __shfl_xor(acc[i], 32);
  wsum += __shfl_xor(wsum, 32);

  if (half == 0) {
    float inv = 1.f / (wsum + 1e-16f);
    int f = j * 8;
    ushort8 o;
    #pragma unroll
    for (int i = 0; i < 8; ++i) {
      float val = (acc[i] * inv + b1[f + i] - mu1[f + i]) *
                  (g1[f + i] * rsqrtf(var1[f + i] + 1e-5f)) + be1[f + i];
      val = (val > 0.f) ? val : (__expf(val) - 1.f);
      o[i] = f2bf(val);
    }
    *(ushort8*)&X2b[(size_t)n * C1 + f] = o;
  }
}

// ---------------------------------------------------------------------------
// GAT agg layer 2: wave per node, 8 edge slots, 16B/lane features.
// ---------------------------------------------------------------------------

__global__ __launch_bounds__(256) void gat2_agg(const unsigned short* __restrict__ H2b,
                                                const float* __restrict__ w,
                                                const int* __restrict__ indptr,
                                                const int* __restrict__ srcs,
                                                const float* __restrict__ b2,
                                                const float* __restrict__ g2,
                                                const float* __restrict__ be2,
                                                const float* __restrict__ mu2,
                                                const float* __restrict__ var2,
                                                float* __restrict__ out, int N) {
  int n = blockIdx.x * 4 + (threadIdx.x >> 6);
  if (n >= N) return;
  int lane = threadIdx.x & 63;
  int q = lane >> 3;
  int j = lane & 7;
  int start = indptr[n], end = indptr[n + 1];

  float acc[8];
  #pragma unroll
  for (int i = 0; i < 8; ++i) acc[i] = 0.f;
  float wsum = 0.f;

  for (int k = start + q; k < end; k += 8) {
    int s = srcs[k];
    float wt = w[k];
    ushort8 raw = *(const ushort8*)&H2b[(size_t)s * HID + j * 8];
    wsum += wt;
    #pragma unroll
    for (int i = 0; i < 8; ++i) acc[i] += wt * bf2f(raw[i]);
  }
  #pragma unroll
  for (int i = 0; i < 8; ++i) {
    acc[i] += __shfl_xor(acc[i], 8);
    acc[i] += __shfl_xor(acc[i], 16);
    acc[i] += __shfl_xor(acc[i], 32);
  }
  wsum += __shfl_xor(wsum, 8);
  wsum += __shfl_xor(wsum, 16);
  wsum += __shfl_xor(wsum, 32);

  if (q == 0) {
    float inv = 1.f / (wsum + 1e-16f);
    int f = j * 8;
    float o[8];
    #pragma unroll
    for (int i = 0; i < 8; ++i) {
      float val = (acc[i] * inv + b2[f + i] - mu2[f + i]) *
                  (g2[f + i] * rsqrtf(var2[f + i] + 1e-5f)) + be2[f + i];
      o[i] = (val > 0.f) ? val : (__expf(val) - 1.f);
    }
    *(float4*)&out[(size_t)n * HID + f]     = make_float4(o[0], o[1], o[2], o[3]);
    *(float4*)&out[(size_t)n * HID + f + 4] = make_float4(o[4], o[5], o[6], o[7]);
  }
}

// ---------------------------------------------------------------------------

extern "C" void kernel_launch(void* const* d_in, const int* in_sizes, int n_in,
                              void* d_out, int out_size, void* d_ws, size_t ws_size,
                              hipStream_t stream) {
  const float* x      = (const float*)d_in[0];
  const int*   ei     = (const int*)d_in[1];
  const float* W1     = (const float*)d_in[2];
  const float* a_src1 = (const float*)d_in[3];
  const float* a_dst1 = (const float*)d_in[4];
  const float* b1     = (const float*)d_in[5];
  const float* g1     = (const float*)d_in[6];
  const float* be1    = (const float*)d_in[7];
  const float* mu1    = (const float*)d_in[8];
  const float* var1   = (const float*)d_in[9];
  const float* W2     = (const float*)d_in[10];
  const float* a_src2 = (const float*)d_in[11];
  const float* a_dst2 = (const float*)d_in[12];
  const float* b2     = (const float*)d_in[13];
  const float* g2     = (const float*)d_in[14];
  const float* be2    = (const float*)d_in[15];
  const float* mu2    = (const float*)d_in[16];
  const float* var2   = (const float*)d_in[17];
  float* out = (float*)d_out;

  int N = in_sizes[0] / IN_DIM;
  int E = in_sizes[1] / 2;
  int Etot = E + N;
  int NB = (N + 1023) / 1024;

  // Workspace (~72 MB):
  //   H1b[N*256]b (reused H2b) | X2b[N*256]b | W1t[256*256]b | W2t[64*256]b |
  //   w1[4*Etot]f (reused w2) | asrc1[4N]f | adst1[4N]f | asrc2[N]f |
  //   adst2[N]f | counts[N] | indptr[N+1] | fillpos[N] | blocksums[NB] |
  //   blockoff[NB+1] | done[1] | srcs[Etot]
  unsigned short* H1b = (unsigned short*)d_ws;
  unsigned short* X2b = H1b + (size_t)N * C1;
  unsigned short* W1t = X2b + (size_t)N * C1;
  unsigned short* W2t = W1t + 256 * 256;
  float* w1    = (float*)(W2t + 64 * 256);
  float* asrc1 = w1 + (size_t)4 * Etot;
  float* adst1 = asrc1 + (size_t)N * HEADS;
  float* asrc2 = adst1 + (size_t)N * HEADS;
  float* adst2 = asrc2 + N;
  int* counts    = (int*)(adst2 + N);
  int* indptr    = counts + N;
  int* fillpos   = indptr + (N + 1);
  int* blocksums = fillpos + N;
  int* blockoff  = blocksums + NB;
  int* done      = blockoff + (NB + 1);
  int* srcs      = done + 1;
  unsigned short* H2b = H1b;   // H1b dead after gat1_agg
  float* w2 = w1;              // w1 dead before edgew2

  // --- prep (weight transposes + zero counts/done) + CSR build ---
  prep_kernel<<<(256 * 256 + 64 * 256 + N + 255) / 256, 256, 0, stream>>>(
      W1, W1t, W2, W2t, counts, done, N);
  hist_kernel<<<(Etot + 255) / 256, 256, 0, stream>>>(ei, E, N, counts);
  scan12_kernel<<<NB, 256, 0, stream>>>(counts, blocksums, blockoff, done, N, NB);
  scan3_kernel<<<NB, 256, 0, stream>>>(counts, blockoff, indptr, fillpos, N, NB);

  // --- Layer 1 ---
  gemm1_fused<<<(N + 127) / 128, 512, 0, stream>>>(x, W1t, H1b, a_src1, a_dst1,
                                                   asrc1, adst1, N);
  fillw_kernel<<<(Etot + 255) / 256, 256, 0, stream>>>(ei, E, N, fillpos, srcs,
                                                       asrc1, adst1, w1);
  gat1_agg<<<(N + 3) / 4, 256, 0, stream>>>(H1b, w1, indptr, srcs,
                                            b1, g1, be1, mu1, var1, X2b, N);

  // --- Layer 2 ---
  gemm2_fused<<<(N + 63) / 64, 256, 0, stream>>>(X2b, W2t, H2b, a_src2, a_dst2,
                                                 asrc2, adst2, N);
  edgew2_kernel<<<(N + 3) / 4, 256, 0, stream>>>(indptr, srcs, asrc2, adst2, w2, N);
  gat2_agg<<<(N + 3) / 4, 256, 0, stream>>>(H2b, w2, indptr, srcs,
                                            b2, g2, be2, mu2, var2, out, N);
}

// Round 12
// 221.099 us; speedup vs baseline: 1.2949x; 1.1016x over previous
//
#include <hip/hip_runtime.h>

#define IN_DIM 256
#define HID 64
#define HEADS 4
#define C1 256   // HID*HEADS

typedef __attribute__((ext_vector_type(4))) float  f32x4;
typedef __attribute__((ext_vector_type(8))) short  short8;
typedef __attribute__((ext_vector_type(8))) unsigned short ushort8;
typedef __attribute__((ext_vector_type(4))) unsigned short ushort4v;

static __device__ __forceinline__ unsigned short f2bf(float f) {
  union { float f; unsigned int u; } v; v.f = f;
  unsigned int r = v.u + 0x7fffu + ((v.u >> 16) & 1u);   // RNE
  return (unsigned short)(r >> 16);
}
static __device__ __forceinline__ float bf2f(unsigned short u) {
  union { unsigned int u; float f; } v; v.u = ((unsigned int)u) << 16;
  return v.f;
}

// ---------------------------------------------------------------------------
// prep: weight transposes (f32 -> bf16, [k][n] -> [n][k]) + zero counts/done
// ---------------------------------------------------------------------------

__global__ __launch_bounds__(256) void prep_kernel(const float* __restrict__ W1,
                                                   unsigned short* __restrict__ W1t,
                                                   const float* __restrict__ W2,
                                                   unsigned short* __restrict__ W2t,
                                                   int* __restrict__ counts,
                                                   int* __restrict__ done, int N) {
  int t = blockIdx.x * 256 + threadIdx.x;
  if (t == 0) *done = 0;
  if (t < 256 * 256) {
    int k = t & 255, n = t >> 8;
    W1t[n * 256 + k] = f2bf(W1[k * 256 + n]);
  } else if (t < 256 * 256 + 64 * 256) {
    int u = t - 256 * 256;
    int k = u & 255, n = u >> 8;
    W2t[n * 256 + k] = f2bf(W2[k * 64 + n]);
  } else {
    int i = t - (256 * 256 + 64 * 256);
    if (i < N) counts[i] = 0;
  }
}

// ---------------------------------------------------------------------------
// CSR build — rank trick: hist returns each edge's rank within its dst.
// ---------------------------------------------------------------------------

__global__ __launch_bounds__(256) void hist_kernel(const int* __restrict__ ei,
                                                   int E, int N,
                                                   int* __restrict__ counts,
                                                   int* __restrict__ rank) {
  int e = blockIdx.x * 256 + threadIdx.x;
  if (e >= E + N) return;
  int dst = (e < E) ? ei[(size_t)E + e] : (e - E);
  rank[e] = atomicAdd(&counts[dst], 1);
}

// scan1 + scan2 fused: per-block sums, last-finishing block scans block sums.
__global__ __launch_bounds__(256) void scan12_kernel(const int* __restrict__ counts,
                                                     int* __restrict__ blocksums,
                                                     int* __restrict__ blockoff,
                                                     int* __restrict__ done,
                                                     int N, int NB) {
  int tid = threadIdx.x;
  int base = blockIdx.x * 1024 + tid * 4;
  int s = 0;
  if (base + 3 < N) {
    int4 v = *(const int4*)&counts[base];
    s = v.x + v.y + v.z + v.w;
  } else {
    for (int i = 0; i < 4; ++i) if (base + i < N) s += counts[base + i];
  }
  __shared__ int red[256];
  red[tid] = s;
  __syncthreads();
  for (int off = 128; off; off >>= 1) {
    if (tid < off) red[tid] += red[tid + off];
    __syncthreads();
  }
  __shared__ int amLast;
  if (tid == 0) {
    blocksums[blockIdx.x] = red[0];
    __threadfence();
    amLast = (atomicAdd(done, 1) == NB - 1);
  }
  __syncthreads();
  if (amLast && tid < 64) {
    __threadfence();
    int lane = tid;
    int carry = 0;
    for (int b = 0; b < NB; b += 64) {
      int v = (b + lane < NB) ? blocksums[b + lane] : 0;
      int incl = v;
      #pragma unroll
      for (int off = 1; off < 64; off <<= 1) {
        int t = __shfl_up(incl, off);
        if (lane >= off) incl += t;
      }
      if (b + lane < NB) blockoff[b + lane] = carry + incl - v;
      carry += __shfl(incl, 63);
    }
    if (lane == 0) blockoff[NB] = carry;
  }
}

__global__ __launch_bounds__(256) void scan3_kernel(const int* __restrict__ counts,
                                                    const int* __restrict__ blockoff,
                                                    int* __restrict__ indptr, int N, int NB) {
  int tid = threadIdx.x;
  int base = blockIdx.x * 1024 + tid * 4;
  int c0 = 0, c1 = 0, c2 = 0, c3 = 0;
  if (base + 3 < N) {
    int4 v = *(const int4*)&counts[base];
    c0 = v.x; c1 = v.y; c2 = v.z; c3 = v.w;
  } else {
    if (base + 0 < N) c0 = counts[base + 0];
    if (base + 1 < N) c1 = counts[base + 1];
    if (base + 2 < N) c2 = counts[base + 2];
    if (base + 3 < N) c3 = counts[base + 3];
  }
  int s = c0 + c1 + c2 + c3;
  __shared__ int sc[256];
  sc[tid] = s;
  __syncthreads();
  for (int off = 1; off < 256; off <<= 1) {
    int t = (tid >= off) ? sc[tid - off] : 0;
    __syncthreads();
    sc[tid] += t;
    __syncthreads();
  }
  int p = sc[tid] - s + blockoff[blockIdx.x];
  if (base + 0 < N) { indptr[base + 0] = p; p += c0; }
  if (base + 1 < N) { indptr[base + 1] = p; p += c1; }
  if (base + 2 < N) { indptr[base + 2] = p; p += c2; }
  if (base + 3 < N) { indptr[base + 3] = p; p += c3; }
  if (blockIdx.x == 0 && tid == 0) indptr[N] = blockoff[NB];
}

// fill (atomic-free via rank) fused with layer-1 edge weights.
__global__ __launch_bounds__(256) void fillw_kernel(const int* __restrict__ ei, int E, int N,
                                                    const int* __restrict__ indptr,
                                                    const int* __restrict__ rank,
                                                    int* __restrict__ srcs,
                                                    const float* __restrict__ asrc,
                                                    const float* __restrict__ adst,
                                                    float* __restrict__ w) {
  int e = blockIdx.x * 256 + threadIdx.x;
  if (e >= E + N) return;
  int src, dst;
  if (e < E) { src = ei[e]; dst = ei[(size_t)E + e]; }
  else       { src = e - E; dst = e - E; }
  int pos = indptr[dst] + rank[e];
  srcs[pos] = src;
  float4 as = *(const float4*)&asrc[src * 4];
  float4 ad = *(const float4*)&adst[dst * 4];
  float e0 = as.x + ad.x; e0 = (e0 > 0.f) ? e0 : 0.2f * e0;
  float e1 = as.y + ad.y; e1 = (e1 > 0.f) ? e1 : 0.2f * e1;
  float e2 = as.z + ad.z; e2 = (e2 > 0.f) ? e2 : 0.2f * e2;
  float e3 = as.w + ad.w; e3 = (e3 > 0.f) ? e3 : 0.2f * e3;
  *(float4*)&w[pos * 4] = make_float4(__expf(e0), __expf(e1), __expf(e2), __expf(e3));
}

// ---------------------------------------------------------------------------
// gemm1 fused: H1b[M,256](bf16) = x[M,256](f32) @ W1t^T, alpha1 in epilogue.
// BM=128, BN=256, BK=64; 512 threads = 8 waves (4 row x 2 col halves).
// ---------------------------------------------------------------------------

#define LDT2 72

__global__ __launch_bounds__(512) void gemm1_fused(const float* __restrict__ A,
                                                   const unsigned short* __restrict__ Bt,
                                                   unsigned short* __restrict__ C,
                                                   const float* __restrict__ a_src,
                                                   const float* __restrict__ a_dst,
                                                   float* __restrict__ asrc,
                                                   float* __restrict__ adst, int M) {
  const int K = 256;
  __shared__ unsigned short As[128 * LDT2];
  __shared__ unsigned short Bs[256 * LDT2];
  int bm = blockIdx.x * 128;
  int tid = threadIdx.x;
  int wid = tid >> 6, lane = tid & 63;
  int wr = (wid >> 1) * 32, wc = (wid & 1) * 128;
  int l15 = lane & 15, lq = lane >> 4;

  f32x4 acc[2][8];
  #pragma unroll
  for (int i = 0; i < 2; ++i)
    #pragma unroll
    for (int f = 0; f < 8; ++f) acc[i][f] = (f32x4){0,0,0,0};

  for (int k0 = 0; k0 < K; k0 += 64) {
    {   // stage A (128 rows x 64 k) with f32->bf16 conversion, 64B/lane
      int r = tid >> 2, c = (tid & 3) * 16;
      int row = bm + r;
      ushort4v o[4];
      #pragma unroll
      for (int p = 0; p < 4; ++p) {
        float4 v = make_float4(0.f, 0.f, 0.f, 0.f);
        if (row < M) v = *(const float4*)&A[(size_t)row * K + k0 + c + p * 4];
        o[p][0]=f2bf(v.x); o[p][1]=f2bf(v.y); o[p][2]=f2bf(v.z); o[p][3]=f2bf(v.w);
      }
      #pragma unroll
      for (int p = 0; p < 4; ++p)
        *(ushort4v*)&As[r * LDT2 + c + p * 4] = o[p];
    }
    #pragma unroll
    for (int p = 0; p < 2; ++p) {   // stage B (256 rows x 64 k)
      int r = p * 128 + (tid >> 2), seg = (tid & 3) * 16;
      ushort8 v0 = *(const ushort8*)&Bt[(size_t)r * K + k0 + seg];
      ushort8 v1 = *(const ushort8*)&Bt[(size_t)r * K + k0 + seg + 8];
      *(ushort8*)&Bs[r * LDT2 + seg]     = v0;
      *(ushort8*)&Bs[r * LDT2 + seg + 8] = v1;
    }
    __syncthreads();

    #pragma unroll
    for (int ks = 0; ks < 2; ++ks) {
      short8 a0 = *(const short8*)&As[(wr + l15) * LDT2 + ks * 32 + lq * 8];
      short8 a1 = *(const short8*)&As[(wr + 16 + l15) * LDT2 + ks * 32 + lq * 8];
      #pragma unroll
      for (int f = 0; f < 8; ++f) {
        short8 b = *(const short8*)&Bs[(wc + f * 16 + l15) * LDT2 + ks * 32 + lq * 8];
        acc[0][f] = __builtin_amdgcn_mfma_f32_16x16x32_bf16(a0, b, acc[0][f], 0, 0, 0);
        acc[1][f] = __builtin_amdgcn_mfma_f32_16x16x32_bf16(a1, b, acc[1][f], 0, 0, 0);
      }
    }
    __syncthreads();
  }

  #pragma unroll
  for (int r = 0; r < 4; ++r) {
    int row0 = bm + wr + lq * 4 + r;
    int row1 = row0 + 16;
    #pragma unroll
    for (int f = 0; f < 8; ++f) {
      int col = wc + f * 16 + l15;
      if (row0 < M) C[(size_t)row0 * 256 + col] = f2bf(acc[0][f][r]);
      if (row1 < M) C[(size_t)row1 * 256 + col] = f2bf(acc[1][f][r]);
    }
  }

  // alpha epilogue: per-(row, head) dot with a_src/a_dst
  float ps[2][4][2], pd[2][4][2];
  #pragma unroll
  for (int i = 0; i < 2; ++i)
    #pragma unroll
    for (int r = 0; r < 4; ++r) { ps[i][r][0]=0.f; ps[i][r][1]=0.f; pd[i][r][0]=0.f; pd[i][r][1]=0.f; }
  #pragma unroll
  for (int f = 0; f < 8; ++f) {
    int col = wc + f * 16 + l15;
    float av = a_src[col], dv = a_dst[col];
    int hh = f >> 2;
    #pragma unroll
    for (int i = 0; i < 2; ++i)
      #pragma unroll
      for (int r = 0; r < 4; ++r) {
        ps[i][r][hh] += acc[i][f][r] * av;
        pd[i][r][hh] += acc[i][f][r] * dv;
      }
  }
  #pragma unroll
  for (int off = 1; off < 16; off <<= 1) {
    #pragma unroll
    for (int i = 0; i < 2; ++i)
      #pragma unroll
      for (int r = 0; r < 4; ++r) {
        ps[i][r][0] += __shfl_xor(ps[i][r][0], off);
        ps[i][r][1] += __shfl_xor(ps[i][r][1], off);
        pd[i][r][0] += __shfl_xor(pd[i][r][0], off);
        pd[i][r][1] += __shfl_xor(pd[i][r][1], off);
      }
  }
  if (l15 == 0) {
    int hb = wc >> 6;   // 0 or 2
    #pragma unroll
    for (int i = 0; i < 2; ++i)
      #pragma unroll
      for (int r = 0; r < 4; ++r) {
        int row = bm + wr + lq * 4 + r + i * 16;
        if (row < M) {
          asrc[row * 4 + hb]     = ps[i][r][0];
          asrc[row * 4 + hb + 1] = ps[i][r][1];
          adst[row * 4 + hb]     = pd[i][r][0];
          adst[row * 4 + hb + 1] = pd[i][r][1];
        }
      }
  }
}

// ---------------------------------------------------------------------------
// gemm2 fused: H2b[M,64](bf16) = X2b[M,256](bf16) @ W2t^T, alpha2 in epilogue.
// ---------------------------------------------------------------------------

__global__ __launch_bounds__(256) void gemm2_fused(const unsigned short* __restrict__ A,
                                                   const unsigned short* __restrict__ Bt,
                                                   unsigned short* __restrict__ C,
                                                   const float* __restrict__ a_src,
                                                   const float* __restrict__ a_dst,
                                                   float* __restrict__ asrc,
                                                   float* __restrict__ adst, int M) {
  const int K = 256;
  __shared__ unsigned short As[64 * LDT2];
  __shared__ unsigned short Bs[64 * LDT2];
  __shared__ float sred[64], dred[64];
  int bm = blockIdx.x * 64;
  int tid = threadIdx.x;
  int wid = tid >> 6, lane = tid & 63;
  int wr = (wid >> 1) * 32, wc = (wid & 1) * 32;
  int l15 = lane & 15, lq = lane >> 4;

  f32x4 acc[2][2];
  #pragma unroll
  for (int i = 0; i < 2; ++i) { acc[i][0] = (f32x4){0,0,0,0}; acc[i][1] = (f32x4){0,0,0,0}; }

  for (int k0 = 0; k0 < K; k0 += 64) {
    {
      int r = tid >> 2, seg = (tid & 3) * 16;
      int row = bm + r;
      ushort8 v0 = {0,0,0,0,0,0,0,0}, v1 = {0,0,0,0,0,0,0,0};
      if (row < M) {
        v0 = *(const ushort8*)&A[(size_t)row * K + k0 + seg];
        v1 = *(const ushort8*)&A[(size_t)row * K + k0 + seg + 8];
      }
      *(ushort8*)&As[r * LDT2 + seg]     = v0;
      *(ushort8*)&As[r * LDT2 + seg + 8] = v1;
    }
    {
      int r = tid >> 2, seg = (tid & 3) * 16;
      ushort8 v0 = *(const ushort8*)&Bt[(size_t)r * K + k0 + seg];
      ushort8 v1 = *(const ushort8*)&Bt[(size_t)r * K + k0 + seg + 8];
      *(ushort8*)&Bs[r * LDT2 + seg]     = v0;
      *(ushort8*)&Bs[r * LDT2 + seg + 8] = v1;
    }
    __syncthreads();

    #pragma unroll
    for (int ks = 0; ks < 2; ++ks) {
      short8 a0 = *(const short8*)&As[(wr + l15) * LDT2 + ks * 32 + lq * 8];
      short8 a1 = *(const short8*)&As[(wr + 16 + l15) * LDT2 + ks * 32 + lq * 8];
      #pragma unroll
      for (int f = 0; f < 2; ++f) {
        short8 b = *(const short8*)&Bs[(wc + f * 16 + l15) * LDT2 + ks * 32 + lq * 8];
        acc[0][f] = __builtin_amdgcn_mfma_f32_16x16x32_bf16(a0, b, acc[0][f], 0, 0, 0);
        acc[1][f] = __builtin_amdgcn_mfma_f32_16x16x32_bf16(a1, b, acc[1][f], 0, 0, 0);
      }
    }
    __syncthreads();
  }

  #pragma unroll
  for (int r = 0; r < 4; ++r) {
    int row0 = bm + wr + lq * 4 + r;
    int row1 = row0 + 16;
    #pragma unroll
    for (int f = 0; f < 2; ++f) {
      int col = wc + f * 16 + l15;
      if (row0 < M) C[(size_t)row0 * 64 + col] = f2bf(acc[0][f][r]);
      if (row1 < M) C[(size_t)row1 * 64 + col] = f2bf(acc[1][f][r]);
    }
  }

  float ps[2][4], pd[2][4];
  #pragma unroll
  for (int i = 0; i < 2; ++i)
    #pragma unroll
    for (int r = 0; r < 4; ++r) { ps[i][r] = 0.f; pd[i][r] = 0.f; }
  #pragma unroll
  for (int f = 0; f < 2; ++f) {
    int col = wc + f * 16 + l15;
    float av = a_src[col], dv = a_dst[col];
    #pragma unroll
    for (int i = 0; i < 2; ++i)
      #pragma unroll
      for (int r = 0; r < 4; ++r) {
        ps[i][r] += acc[i][f][r] * av;
        pd[i][r] += acc[i][f][r] * dv;
      }
  }
  #pragma unroll
  for (int off = 1; off < 16; off <<= 1) {
    #pragma unroll
    for (int i = 0; i < 2; ++i)
      #pragma unroll
      for (int r = 0; r < 4; ++r) {
        ps[i][r] += __shfl_xor(ps[i][r], off);
        pd[i][r] += __shfl_xor(pd[i][r], off);
      }
  }
  if ((wid & 1) == 0 && l15 == 0) {
    #pragma unroll
    for (int i = 0; i < 2; ++i)
      #pragma unroll
      for (int r = 0; r < 4; ++r) {
        int rl = wr + lq * 4 + r + i * 16;
        sred[rl] = ps[i][r];
        dred[rl] = pd[i][r];
      }
  }
  __syncthreads();
  if ((wid & 1) == 1 && l15 == 0) {
    #pragma unroll
    for (int i = 0; i < 2; ++i)
      #pragma unroll
      for (int r = 0; r < 4; ++r) {
        int rl = wr + lq * 4 + r + i * 16;
        int row = bm + rl;
        if (row < M) {
          asrc[row] = sred[rl] + ps[i][r];
          adst[row] = dred[rl] + pd[i][r];
        }
      }
  }
}

// ---------------------------------------------------------------------------
// Layer-2 edge weights, dst-major (wave per node)
// ---------------------------------------------------------------------------

__global__ __launch_bounds__(256) void edgew2_kernel(const int* __restrict__ indptr,
                                                     const int* __restrict__ srcs,
                                                     const float* __restrict__ asrc,
                                                     const float* __restrict__ adst,
                                                     float* __restrict__ w, int N) {
  int n = blockIdx.x * 4 + (threadIdx.x >> 6);
  if (n >= N) return;
  int lane = threadIdx.x & 63;
  int start = indptr[n], end = indptr[n + 1];
  float ad = adst[n];
  for (int k = start + lane; k < end; k += 64) {
    float e = asrc[srcs[k]] + ad;
    e = (e > 0.f) ? e : 0.2f * e;
    w[k] = __expf(e);
  }
}

// ---------------------------------------------------------------------------
// GAT agg layer 1: wave per node, split-wave (2 edges), 16B/lane, 4x unroll.
// ---------------------------------------------------------------------------

__global__ __launch_bounds__(256) void gat1_agg(const unsigned short* __restrict__ H1b,
                                                const float* __restrict__ w,
                                                const int* __restrict__ indptr,
                                                const int* __restrict__ srcs,
                                                const float* __restrict__ b1,
                                                const float* __restrict__ g1,
                                                const float* __restrict__ be1,
                                                const float* __restrict__ mu1,
                                                const float* __restrict__ var1,
                                                unsigned short* __restrict__ X2b, int N) {
  int n = blockIdx.x * 4 + (threadIdx.x >> 6);
  if (n >= N) return;
  int lane = threadIdx.x & 63;
  int half = lane >> 5;
  int j = lane & 31;
  int h = j >> 3;
  int start = indptr[n], end = indptr[n + 1];

  float acc[8] = {0.f,0.f,0.f,0.f,0.f,0.f,0.f,0.f};
  float wsum = 0.f;
  int k = start + half;
  // 4 edges per half-wave in flight (8 per wave)
  for (; k + 6 < end; k += 8) {
    int s0 = srcs[k], s1 = srcs[k + 2], s2 = srcs[k + 4], s3 = srcs[k + 6];
    float w0 = w[k * 4 + h], w1v = w[(k + 2) * 4 + h];
    float w2v = w[(k + 4) * 4 + h], w3v = w[(k + 6) * 4 + h];
    ushort8 r0 = *(const ushort8*)&H1b[(size_t)s0 * C1 + j * 8];
    ushort8 r1 = *(const ushort8*)&H1b[(size_t)s1 * C1 + j * 8];
    ushort8 r2 = *(const ushort8*)&H1b[(size_t)s2 * C1 + j * 8];
    ushort8 r3 = *(const ushort8*)&H1b[(size_t)s3 * C1 + j * 8];
    wsum += (w0 + w1v) + (w2v + w3v);
    #pragma unroll
    for (int i = 0; i < 8; ++i)
      acc[i] += (w0 * bf2f(r0[i]) + w1v * bf2f(r1[i])) +
                (w2v * bf2f(r2[i]) + w3v * bf2f(r3[i]));
  }
  for (; k < end; k += 2) {
    int s0 = srcs[k];
    float w0 = w[k * 4 + h];
    ushort8 r0 = *(const ushort8*)&H1b[(size_t)s0 * C1 + j * 8];
    wsum += w0;
    #pragma unroll
    for (int i = 0; i < 8; ++i) acc[i] += w0 * bf2f(r0[i]);
  }
  #pragma unroll
  for (int i = 0; i < 8; ++i) acc[i] += __shfl_xor(acc[i], 32);
  wsum += __shfl_xor(wsum, 32);

  if (half == 0) {
    float inv = 1.f / (wsum + 1e-16f);
    int f = j * 8;
    ushort8 o;
    #pragma unroll
    for (int i = 0; i < 8; ++i) {
      float val = (acc[i] * inv + b1[f + i] - mu1[f + i]) *
                  (g1[f + i] * rsqrtf(var1[f + i] + 1e-5f)) + be1[f + i];
      val = (val > 0.f) ? val : (__expf(val) - 1.f);
      o[i] = f2bf(val);
    }
    *(ushort8*)&X2b[(size_t)n * C1 + f] = o;
  }
}

// ---------------------------------------------------------------------------
// GAT agg layer 2: wave per node, 8 edge slots, 16B/lane, 2x unroll.
// ---------------------------------------------------------------------------

__global__ __launch_bounds__(256) void gat2_agg(const unsigned short* __restrict__ H2b,
                                                const float* __restrict__ w,
                                                const int* __restrict__ indptr,
                                                const int* __restrict__ srcs,
                                                const float* __restrict__ b2,
                                                const float* __restrict__ g2,
                                                const float* __restrict__ be2,
                                                const float* __restrict__ mu2,
                                                const float* __restrict__ var2,
                                                float* __restrict__ out, int N) {
  int n = blockIdx.x * 4 + (threadIdx.x >> 6);
  if (n >= N) return;
  int lane = threadIdx.x & 63;
  int q = lane >> 3;
  int j = lane & 7;
  int start = indptr[n], end = indptr[n + 1];

  float acc[8];
  #pragma unroll
  for (int i = 0; i < 8; ++i) acc[i] = 0.f;
  float wsum = 0.f;

  int k = start + q;
  for (; k + 8 < end; k += 16) {
    int s0 = srcs[k], s1 = srcs[k + 8];
    float w0 = w[k], w1v = w[k + 8];
    ushort8 r0 = *(const ushort8*)&H2b[(size_t)s0 * HID + j * 8];
    ushort8 r1 = *(const ushort8*)&H2b[(size_t)s1 * HID + j * 8];
    wsum += w0 + w1v;
    #pragma unroll
    for (int i = 0; i < 8; ++i)
      acc[i] += w0 * bf2f(r0[i]) + w1v * bf2f(r1[i]);
  }
  if (k < end) {
    float w0 = w[k];
    ushort8 r0 = *(const ushort8*)&H2b[(size_t)srcs[k] * HID + j * 8];
    wsum += w0;
    #pragma unroll
    for (int i = 0; i < 8; ++i) acc[i] += w0 * bf2f(r0[i]);
  }
  #pragma unroll
  for (int i = 0; i < 8; ++i) {
    acc[i] += __shfl_xor(acc[i], 8);
    acc[i] += __shfl_xor(acc[i], 16);
    acc[i] += __shfl_xor(acc[i], 32);
  }
  wsum += __shfl_xor(wsum, 8);
  wsum += __shfl_xor(wsum, 16);
  wsum += __shfl_xor(wsum, 32);

  if (q == 0) {
    float inv = 1.f / (wsum + 1e-16f);
    int f = j * 8;
    float o[8];
    #pragma unroll
    for (int i = 0; i < 8; ++i) {
      float val = (acc[i] * inv + b2[f + i] - mu2[f + i]) *
                  (g2[f + i] * rsqrtf(var2[f + i] + 1e-5f)) + be2[f + i];
      o[i] = (val > 0.f) ? val : (__expf(val) - 1.f);
    }
    *(float4*)&out[(size_t)n * HID + f]     = make_float4(o[0], o[1], o[2], o[3]);
    *(float4*)&out[(size_t)n * HID + f + 4] = make_float4(o[4], o[5], o[6], o[7]);
  }
}

// ---------------------------------------------------------------------------

extern "C" void kernel_launch(void* const* d_in, const int* in_sizes, int n_in,
                              void* d_out, int out_size, void* d_ws, size_t ws_size,
                              hipStream_t stream) {
  const float* x      = (const float*)d_in[0];
  const int*   ei     = (const int*)d_in[1];
  const float* W1     = (const float*)d_in[2];
  const float* a_src1 = (const float*)d_in[3];
  const float* a_dst1 = (const float*)d_in[4];
  const float* b1     = (const float*)d_in[5];
  const float* g1     = (const float*)d_in[6];
  const float* be1    = (const float*)d_in[7];
  const float* mu1    = (const float*)d_in[8];
  const float* var1   = (const float*)d_in[9];
  const float* W2     = (const float*)d_in[10];
  const float* a_src2 = (const float*)d_in[11];
  const float* a_dst2 = (const float*)d_in[12];
  const float* b2     = (const float*)d_in[13];
  const float* g2     = (const float*)d_in[14];
  const float* be2    = (const float*)d_in[15];
  const float* mu2    = (const float*)d_in[16];
  const float* var2   = (const float*)d_in[17];
  float* out = (float*)d_out;

  int N = in_sizes[0] / IN_DIM;
  int E = in_sizes[1] / 2;
  int Etot = E + N;
  int NB = (N + 1023) / 1024;

  // Workspace (~72 MB):
  //   H1b[N*256]b (reused H2b) | X2b[N*256]b | W1t[256*256]b | W2t[64*256]b |
  //   w1[4*Etot]f (reused w2) | asrc1[4N]f | adst1[4N]f | asrc2[N]f |
  //   adst2[N]f | counts[N] | indptr[N+1] | blocksums[NB] | blockoff[NB+1] |
  //   done[1] | rank[Etot] | srcs[Etot]
  unsigned short* H1b = (unsigned short*)d_ws;
  unsigned short* X2b = H1b + (size_t)N * C1;
  unsigned short* W1t = X2b + (size_t)N * C1;
  unsigned short* W2t = W1t + 256 * 256;
  float* w1    = (float*)(W2t + 64 * 256);
  float* asrc1 = w1 + (size_t)4 * Etot;
  float* adst1 = asrc1 + (size_t)N * HEADS;
  float* asrc2 = adst1 + (size_t)N * HEADS;
  float* adst2 = asrc2 + N;
  int* counts    = (int*)(adst2 + N);
  int* indptr    = counts + N;
  int* blocksums = indptr + (N + 1);
  int* blockoff  = blocksums + NB;
  int* done      = blockoff + (NB + 1);
  int* rank      = done + 1;
  int* srcs      = rank + Etot;
  unsigned short* H2b = H1b;   // H1b dead after gat1_agg
  float* w2 = w1;              // w1 dead before edgew2

  // --- prep + CSR build (rank trick) ---
  prep_kernel<<<(256 * 256 + 64 * 256 + N + 255) / 256, 256, 0, stream>>>(
      W1, W1t, W2, W2t, counts, done, N);
  hist_kernel<<<(Etot + 255) / 256, 256, 0, stream>>>(ei, E, N, counts, rank);
  scan12_kernel<<<NB, 256, 0, stream>>>(counts, blocksums, blockoff, done, N, NB);
  scan3_kernel<<<NB, 256, 0, stream>>>(counts, blockoff, indptr, N, NB);

  // --- Layer 1 ---
  gemm1_fused<<<(N + 127) / 128, 512, 0, stream>>>(x, W1t, H1b, a_src1, a_dst1,
                                                   asrc1, adst1, N);
  fillw_kernel<<<(Etot + 255) / 256, 256, 0, stream>>>(ei, E, N, indptr, rank, srcs,
                                                       asrc1, adst1, w1);
  gat1_agg<<<(N + 3) / 4, 256, 0, stream>>>(H1b, w1, indptr, srcs,
                                            b1, g1, be1, mu1, var1, X2b, N);

  // --- Layer 2 ---
  gemm2_fused<<<(N + 63) / 64, 256, 0, stream>>>(X2b, W2t, H2b, a_src2, a_dst2,
                                                 asrc2, adst2, N);
  edgew2_kernel<<<(N + 3) / 4, 256, 0, stream>>>(indptr, srcs, asrc2, adst2, w2, N);
  gat2_agg<<<(N + 3) / 4, 256, 0, stream>>>(H2b, w2, indptr, srcs,
                                            b2, g2, be2, mu2, var2, out, N);
}